// Round 1
// baseline (1056.339 us; speedup 1.0000x reference)
//
#include <hip/hip_runtime.h>
#include <hip/hip_bf16.h>

typedef __bf16 bf16;
typedef __attribute__((ext_vector_type(8))) __bf16 bf16x8;
typedef __attribute__((ext_vector_type(4))) float floatx4;

constexpr int CB = 8, CS = 256, CD = 1024, CH = 16, CE = 4, CFF = 4096, CHD = 64;
constexpr long long DD = 1048576;      // D*D
constexpr long long DFF = 4194304;     // D*FF
constexpr long long BSD = 2097152;     // B*S*D

// ---------- workspace layout (bytes) ----------
constexpr size_t OFF_XS     = 0;                       // 8192 f
constexpr size_t OFF_CLEAN  = 32768;                   // 32 f
constexpr size_t OFF_RAW    = 32896;                   // 32 f
constexpr size_t OFF_GATES  = 33024;                   // 32 f
constexpr size_t OFF_EACT   = 33152;                   // 4 int
constexpr size_t OFF_XBF    = 33280;                   // 2M bf16
constexpr size_t OFF_WQKVOT = OFF_XBF + BSD*2;         // 4 x D*D bf16
constexpr size_t OFF_W1T    = OFF_WQKVOT + 4*DD*2;     // D*FF bf16
constexpr size_t OFF_W2T    = OFF_W1T + DFF*2;         // D*FF bf16
constexpr size_t OFF_QKV    = OFF_W2T + DFF*2;         // 3 x B*S*D bf16
constexpr size_t OFF_VT     = OFF_QKV + 3*BSD*2;       // B*S*D bf16 (b,h,hd,s)
constexpr size_t OFF_F1     = OFF_QKV;                 // ALIAS: f1 (16.8MB) over qkv+vT (dead by FF1)
constexpr size_t OFF_P      = OFF_VT + BSD*2;          // B*H*S*S bf16 (16.8MB)
constexpr size_t OFF_TMP    = OFF_P;                   // ALIAS: tmp f32 (8.4MB) over P (dead by Wo)
constexpr size_t OFF_AO     = OFF_P + 16777216;        // B*S*D bf16
constexpr size_t OFF_H      = OFF_AO + BSD*2;          // B*S*D f32
constexpr size_t OFF_HBF    = OFF_H + BSD*4;           // B*S*D bf16
// total = OFF_HBF + BSD*2 = 79,725,056 bytes (~76 MB)

// ---------- small kernels ----------
__global__ void zero_y(float* y) { int i = blockIdx.x*256 + threadIdx.x; y[i] = 0.f; }

__global__ void epsfill(float* y) {
  int i = blockIdx.x*256 + threadIdx.x;
  if (y[i] == 0.f) y[i] = 2.2204460492503131e-16f;
}

__global__ void cvt_bf16(const float* __restrict__ in, bf16* __restrict__ out) {
  int i = blockIdx.x*256 + threadIdx.x; out[i] = (bf16)in[i];
}

__global__ void xsum_kernel(const float* __restrict__ x, float* __restrict__ xs) {
  int i = blockIdx.x*256 + threadIdx.x;     // 0..8191
  int b = i >> 10, d = i & 1023;
  float s = 0.f;
  for (int t = 0; t < CS; ++t) s += x[((long)(b*CS + t))*CD + d];
  xs[i] = s;
}

__global__ void gate_dots(const float* __restrict__ xs, const float* __restrict__ wg,
                          const float* __restrict__ wn, float* __restrict__ clean,
                          float* __restrict__ raw) {
  int t = threadIdx.x; int p = t >> 3, i = t & 7;   // p: (b,e) pair, i: 1/8 of D
  int b = p >> 2, e = p & 3;
  float s1 = 0.f, s2 = 0.f;
  for (int d = i*128; d < i*128 + 128; ++d) {
    float xv = xs[b*CD + d];
    s1 += xv * wg[d*CE + e];
    s2 += xv * wn[d*CE + e];
  }
  __shared__ float r1[256], r2[256];
  r1[t] = s1; r2[t] = s2;
  __syncthreads();
  if (i == 0) {
    float a = 0.f, c = 0.f;
    for (int j = 0; j < 8; ++j) { a += r1[p*8 + j]; c += r2[p*8 + j]; }
    clean[p] = a; raw[p] = c;
  }
}

__global__ void gating_kernel(const float* __restrict__ clean, const float* __restrict__ raw,
                              const float* __restrict__ noise, float* __restrict__ gates,
                              int* __restrict__ eact, float* __restrict__ loss_out) {
  if (threadIdx.x != 0) return;
  float imp[CE] = {0,0,0,0}, load[CE] = {0,0,0,0};
  int act[CE] = {0,0,0,0};
  for (int b = 0; b < CB; ++b) {
    float cl[CE], sd[CE], ny[CE];
    for (int e = 0; e < CE; ++e) {
      cl[e] = clean[b*CE + e];
      float rw = raw[b*CE + e];
      float sp = fmaxf(rw, 0.f) + log1pf(expf(-fabsf(rw)));   // stable softplus
      sd[e] = sp + 0.01f;
      ny[e] = cl[e] + noise[b*CE + e]*sd[e];
    }
    int idx[CE] = {0,1,2,3};
    for (int a = 0; a < 3; ++a) {            // selection sort desc, stable (ties -> lower idx)
      int best = a;
      for (int c = a + 1; c < 4; ++c) if (ny[idx[c]] > ny[idx[best]]) best = c;
      int tt = idx[a]; idx[a] = idx[best]; idx[best] = tt;
    }
    float l0 = ny[idx[0]], l1 = ny[idx[1]], l2 = ny[idx[2]];
    float e1 = expf(l1 - l0);
    float g0 = 1.f/(1.f + e1), g1v = e1/(1.f + e1);
    for (int e = 0; e < CE; ++e) gates[b*CE + e] = 0.f;
    gates[b*CE + idx[0]] = g0; gates[b*CE + idx[1]] = g1v;
    imp[idx[0]] += g0; imp[idx[1]] += g1v;
    act[idx[0]] = 1; act[idx[1]] = 1;
    for (int e = 0; e < CE; ++e) {
      bool is_in = ny[e] > l2;
      float thr = is_in ? l2 : l1;
      float zz = (cl[e] - thr) / sd[e];
      load[e] += 0.5f * erfcf(-zz * 0.70710678118654752440f);  // Phi(zz)
    }
  }
  float m1 = 0.f, m2 = 0.f;
  for (int e = 0; e < CE; ++e) { m1 += imp[e]; m2 += load[e]; }
  m1 *= 0.25f; m2 *= 0.25f;
  float v1 = 0.f, v2 = 0.f;
  for (int e = 0; e < CE; ++e) { float d1 = imp[e]-m1, d2 = load[e]-m2; v1 += d1*d1; v2 += d2*d2; }
  v1 *= (1.f/3.f); v2 *= (1.f/3.f);          // ddof=1
  loss_out[0] = 0.01f * (v1/(m1*m1 + 1e-10f) + v2/(m2*m2 + 1e-10f));
  for (int e = 0; e < CE; ++e) eact[e] = act[e];
}

// transpose+convert: src fp32 (rows x cols) -> dst bf16 (cols x rows); z selects src, dst += z*dstStride
__global__ __launch_bounds__(256)
void transcvt(const float* __restrict__ s0, const float* __restrict__ s1,
              const float* __restrict__ s2, const float* __restrict__ s3,
              bf16* __restrict__ dst, int rows, int cols, long long dstStride,
              const int* __restrict__ flag) {
  if (*flag == 0) return;
  int z = blockIdx.z;
  const float* src = (z == 0) ? s0 : (z == 1) ? s1 : (z == 2) ? s2 : s3;
  __shared__ float tile[32][33];
  int c0 = blockIdx.x*32, r0 = blockIdx.y*32;
  int tx = threadIdx.x, ty = threadIdx.y;
#pragma unroll
  for (int i = 0; i < 4; ++i)
    tile[ty + 8*i][tx] = src[(long)(r0 + ty + 8*i)*cols + c0 + tx];
  __syncthreads();
#pragma unroll
  for (int i = 0; i < 4; ++i)
    dst[z*dstStride + (long)(c0 + ty + 8*i)*rows + r0 + tx] = (bf16)tile[tx][ty + 8*i];
}

// v (b,s,h,hd) bf16 -> vT (b,h,hd,s) bf16
__global__ __launch_bounds__(256)
void transpose_v(const bf16* __restrict__ v, bf16* __restrict__ vt,
                 const float* __restrict__ gates, int expert) {
  int z = blockIdx.z; int b = z / CH, h = z % CH;
  if (gates[b*CE + expert] == 0.f) return;
  __shared__ bf16 tile[32][33];
  int s0 = blockIdx.x*32, d0 = blockIdx.y*32;
  int tx = threadIdx.x, ty = threadIdx.y;
#pragma unroll
  for (int i = 0; i < 4; ++i)
    tile[ty + 8*i][tx] = v[((long)(b*CS + s0 + ty + 8*i))*CD + h*CHD + d0 + tx];
  __syncthreads();
#pragma unroll
  for (int i = 0; i < 4; ++i)
    vt[(long)z*CHD*CS + (long)(d0 + ty + 8*i)*CS + s0 + tx] = tile[tx][ty + 8*i];
}

// causal softmax, in-place on bf16 scores row; scale applied here
__global__ __launch_bounds__(64)
void softmax_causal(bf16* __restrict__ P, const float* __restrict__ gates, int expert, float scale) {
  int q = blockIdx.x, z = blockIdx.y;
  int b = z / CH;
  if (gates[b*CE + expert] == 0.f) return;
  bf16* row = P + (long)z*CS*CS + (long)q*CS;
  int t = threadIdx.x;
  float v[4];
#pragma unroll
  for (int i = 0; i < 4; ++i) {
    int k = t + 64*i;
    v[i] = (k <= q) ? (float)row[k]*scale : -3.0e38f;
  }
  float mx = fmaxf(fmaxf(v[0], v[1]), fmaxf(v[2], v[3]));
  for (int off = 32; off; off >>= 1) mx = fmaxf(mx, __shfl_xor(mx, off));
  float p[4], sum = 0.f;
#pragma unroll
  for (int i = 0; i < 4; ++i) { p[i] = __expf(v[i] - mx); sum += p[i]; }
  for (int off = 32; off; off >>= 1) sum += __shfl_xor(sum, off);
  float inv = 1.f / sum;
#pragma unroll
  for (int i = 0; i < 4; ++i) {
    int k = t + 64*i;
    row[k] = (bf16)((k <= q) ? p[i]*inv : 0.f);
  }
}

// layernorm over D of (ina+inb); ACC=false: write f32+bf16; ACC=true: y += gate*ln
template<bool ACC>
__global__ __launch_bounds__(256)
void ln_kernel(const float* __restrict__ ina, const float* __restrict__ inb,
               const float* __restrict__ gamma, const float* __restrict__ beta,
               float* __restrict__ outf, bf16* __restrict__ outbf,
               float* __restrict__ yacc, const float* __restrict__ gates, int expert) {
  int row = blockIdx.x;
  int b = row / CS;
  float g = gates[b*CE + expert];
  if (g == 0.f) return;
  int t = threadIdx.x;
  const float* pa = ina + (long)row*CD;
  const float* pb = inb + (long)row*CD;
  float v[4]; float s = 0.f, s2 = 0.f;
#pragma unroll
  for (int i = 0; i < 4; ++i) {
    int d = t + 256*i;
    float xv = pa[d] + pb[d];
    v[i] = xv; s += xv; s2 += xv*xv;
  }
  int lane = t & 63, wave = t >> 6;
  for (int off = 32; off; off >>= 1) { s += __shfl_xor(s, off); s2 += __shfl_xor(s2, off); }
  __shared__ float red[8];
  if (lane == 0) { red[wave*2] = s; red[wave*2 + 1] = s2; }
  __syncthreads();
  s  = red[0] + red[2] + red[4] + red[6];
  s2 = red[1] + red[3] + red[5] + red[7];
  float mean = s * (1.f/CD);
  float var  = s2 * (1.f/CD) - mean*mean;
  float rstd = rsqrtf(var + 1e-5f);
#pragma unroll
  for (int i = 0; i < 4; ++i) {
    int d = t + 256*i;
    float val = (v[i] - mean)*rstd*gamma[d] + beta[d];
    if constexpr (ACC) yacc[(long)row*CD + d] += g*val;
    else { outf[(long)row*CD + d] = val; outbf[(long)row*CD + d] = (bf16)val; }
  }
}

// ---------- MFMA GEMM:  C[M,N] = A[M,K] * Bt[N,K]^T  (both bf16, k-contiguous) ----------
// XOR-swizzled LDS: row r slot p (16B) holds k-chunk (p ^ (r&7)) -> <=2-way bank alias on r/w.
template<int R>
__device__ __forceinline__ void stage_tile(const bf16* __restrict__ src, int ld, bf16* dst) {
  int t = threadIdx.x;
  int s = t & 7;
  int rb = t >> 3;
#pragma unroll
  for (int i = 0; i < R/32; ++i) {
    int r = i*32 + rb;
    bf16x8 v = *(const bf16x8*)(src + (long)r*ld + s*8);
    *(bf16x8*)(dst + r*64 + ((s ^ (r & 7))*8)) = v;
  }
}

enum { EPI_BF16 = 0, EPI_F32 = 1, EPI_BRELU = 2, EPI_BIASF32 = 3 };

template<int BM, int BN, int EPI, bool CAUSAL, bool GATE_Z>
__global__ __launch_bounds__(256)
void gemm_nt(const bf16* __restrict__ A, const bf16* __restrict__ Bt, void* __restrict__ Cv,
             int K, int lda, int ldb, int ldc,
             long long oA1, long long oA2, long long oB1, long long oB2,
             long long oC1, long long oC2, int zdiv,
             const float* __restrict__ bias,
             const float* __restrict__ gates, int expert) {
  int z = blockIdx.z;
  int zq = z / zdiv, zr = z % zdiv;
  int m0 = blockIdx.y * BM, n0 = blockIdx.x * BN;
  if (CAUSAL && n0 > m0) return;
  int gb = GATE_Z ? zq : (m0 / CS);
  if (gates[gb*CE + expert] == 0.f) return;
  A  += zq*oA1 + zr*oA2;
  Bt += zq*oB1 + zr*oB2;
  long long coff = zq*oC1 + zr*oC2;

  __shared__ bf16 As[BM*64];
  __shared__ bf16 Bs[BN*64];

  int wave = threadIdx.x >> 6;
  int lane = threadIdx.x & 63;
  constexpr int WN = BN/64;
  int wm = wave / WN, wn = wave % WN;
  int lr = lane & 15;
  int quad = lane >> 4;

  floatx4 acc[4][4] = {};

  for (int kt = 0; kt < K; kt += 64) {
    stage_tile<BM>(A  + (long)m0*lda + kt, lda, As);
    stage_tile<BN>(Bt + (long)n0*ldb + kt, ldb, Bs);
    __syncthreads();
#pragma unroll
    for (int kk = 0; kk < 2; ++kk) {
      bf16x8 af[4], bfr[4];
#pragma unroll
      for (int i = 0; i < 4; ++i) {
        int c = kk*4 + quad;
        int m = wm*64 + i*16 + lr;
        af[i]  = *(const bf16x8*)(As + m*64 + ((c ^ (m & 7))*8));
        int n = wn*64 + i*16 + lr;
        bfr[i] = *(const bf16x8*)(Bs + n*64 + ((c ^ (n & 7))*8));
      }
#pragma unroll
      for (int i = 0; i < 4; ++i)
#pragma unroll
        for (int j = 0; j < 4; ++j)
          acc[i][j] = __builtin_amdgcn_mfma_f32_16x16x32_bf16(af[i], bfr[j], acc[i][j], 0, 0, 0);
    }
    __syncthreads();
  }

#pragma unroll
  for (int j = 0; j < 4; ++j) {
    int col = n0 + wn*64 + j*16 + lr;
    float bv = 0.f;
    if constexpr (EPI == EPI_BRELU || EPI == EPI_BIASF32) bv = bias[col];
#pragma unroll
    for (int i = 0; i < 4; ++i) {
#pragma unroll
      for (int r = 0; r < 4; ++r) {
        int row = m0 + wm*64 + i*16 + quad*4 + r;
        float v = acc[i][j][r] + bv;
        long long idx = coff + (long long)row*ldc + col;
        if constexpr (EPI == EPI_BF16)        ((bf16*)Cv)[idx] = (bf16)v;
        else if constexpr (EPI == EPI_F32)    ((float*)Cv)[idx] = v;
        else if constexpr (EPI == EPI_BRELU)  ((bf16*)Cv)[idx] = (bf16)fmaxf(v, 0.f);
        else                                  ((float*)Cv)[idx] = v;
      }
    }
  }
}

// ---------- launch ----------
extern "C" void kernel_launch(void* const* d_in, const int* in_sizes, int n_in,
                              void* d_out, int out_size, void* d_ws, size_t ws_size,
                              hipStream_t stream) {
  const float* x       = (const float*)d_in[0];
  const float* noise   = (const float*)d_in[2];
  const float* w_gate  = (const float*)d_in[3];
  const float* w_noise = (const float*)d_in[4];
  const float* Wq      = (const float*)d_in[5];
  const float* Wk      = (const float*)d_in[6];
  const float* Wv      = (const float*)d_in[7];
  const float* Wo      = (const float*)d_in[8];
  const float* W1      = (const float*)d_in[9];
  const float* b1      = (const float*)d_in[10];
  const float* W2      = (const float*)d_in[11];
  const float* b2      = (const float*)d_in[12];
  const float* g1      = (const float*)d_in[13];
  const float* be1     = (const float*)d_in[14];
  const float* g2      = (const float*)d_in[15];
  const float* be2     = (const float*)d_in[16];

  char* ws = (char*)d_ws;
  float* y    = (float*)d_out;                 // 2,097,152 floats
  float* loss = y + (size_t)BSD;

  float* xs    = (float*)(ws + OFF_XS);
  float* clean = (float*)(ws + OFF_CLEAN);
  float* raw   = (float*)(ws + OFF_RAW);
  float* gates = (float*)(ws + OFF_GATES);
  int*   eact  = (int*)  (ws + OFF_EACT);
  bf16*  xbf   = (bf16*) (ws + OFF_XBF);
  bf16*  wqkvoT= (bf16*) (ws + OFF_WQKVOT);
  bf16*  w1T   = (bf16*) (ws + OFF_W1T);
  bf16*  w2T   = (bf16*) (ws + OFF_W2T);
  bf16*  qkv   = (bf16*) (ws + OFF_QKV);
  bf16*  vT    = (bf16*) (ws + OFF_VT);
  bf16*  f1    = (bf16*) (ws + OFF_F1);
  bf16*  P     = (bf16*) (ws + OFF_P);
  float* tmp   = (float*)(ws + OFF_TMP);
  bf16*  ao    = (bf16*) (ws + OFF_AO);
  float* h     = (float*)(ws + OFF_H);
  bf16*  hbf   = (bf16*) (ws + OFF_HBF);

  zero_y<<<8192, 256, 0, stream>>>(y);
  xsum_kernel<<<32, 256, 0, stream>>>(x, xs);
  gate_dots<<<1, 256, 0, stream>>>(xs, w_gate, w_noise, clean, raw);
  gating_kernel<<<1, 64, 0, stream>>>(clean, raw, noise, gates, eact, loss);
  cvt_bf16<<<8192, 256, 0, stream>>>(x, xbf);

  for (int e = 0; e < CE; ++e) {
    // weight transpose+convert (skipped entirely if expert inactive)
    transcvt<<<dim3(32, 32, 4), dim3(32, 8), 0, stream>>>(
        Wq + e*DD, Wk + e*DD, Wv + e*DD, Wo + e*DD, wqkvoT, 1024, 1024, DD, eact + e);
    transcvt<<<dim3(128, 32, 1), dim3(32, 8), 0, stream>>>(
        W1 + e*DFF, W1, W1, W1, w1T, 1024, 4096, 0LL, eact + e);
    transcvt<<<dim3(32, 128, 1), dim3(32, 8), 0, stream>>>(
        W2 + e*DFF, W2, W2, W2, w2T, 4096, 1024, 0LL, eact + e);

    // q,k,v = x @ {Wq,Wk,Wv}   (z batches the three)
    gemm_nt<128, 128, EPI_BF16, false, false><<<dim3(8, 16, 3), 256, 0, stream>>>(
        xbf, wqkvoT, qkv, 1024, 1024, 1024, 1024,
        0LL, 0LL, DD, 0LL, BSD, 0LL, 1, nullptr, gates, e);

    transpose_v<<<dim3(8, 2, 128), dim3(32, 8), 0, stream>>>(qkv + 2*BSD, vT, gates, e);

    // scores = q @ k^T  (per (b,h); causal block skip; raw logits stored bf16)
    gemm_nt<128, 128, EPI_BF16, true, true><<<dim3(2, 2, 128), 256, 0, stream>>>(
        qkv, qkv + BSD, P, 64, 1024, 1024, 256,
        (long long)CS*CD, 64LL, (long long)CS*CD, 64LL,
        (long long)CH*CS*CS, (long long)CS*CS, CH, nullptr, gates, e);

    softmax_causal<<<dim3(256, 128), 64, 0, stream>>>(P, gates, e, 0.125f);

    // ao = P @ v   (per (b,h))
    gemm_nt<256, 64, EPI_BF16, false, true><<<dim3(1, 1, 128), 256, 0, stream>>>(
        P, vT, ao, 256, 256, 256, 1024,
        (long long)CH*CS*CS, (long long)CS*CS,
        (long long)CH*CHD*CS, (long long)CHD*CS,
        (long long)CS*CD, 64LL, CH, nullptr, gates, e);

    // o = ao @ Wo
    gemm_nt<128, 128, EPI_F32, false, false><<<dim3(8, 16, 1), 256, 0, stream>>>(
        ao, wqkvoT + 3*DD, tmp, 1024, 1024, 1024, 1024,
        0LL, 0LL, 0LL, 0LL, 0LL, 0LL, 1, nullptr, gates, e);

    // h = LN(x + o)
    ln_kernel<false><<<2048, 256, 0, stream>>>(x, tmp, g1 + e*CD, be1 + e*CD, h, hbf, nullptr, gates, e);

    // f1 = relu(h @ W1 + b1)
    gemm_nt<128, 128, EPI_BRELU, false, false><<<dim3(32, 16, 1), 256, 0, stream>>>(
        hbf, w1T, f1, 1024, 1024, 1024, 4096,
        0LL, 0LL, 0LL, 0LL, 0LL, 0LL, 1, b1 + e*CFF, gates, e);

    // f2 = f1 @ W2 + b2
    gemm_nt<128, 128, EPI_BIASF32, false, false><<<dim3(8, 16, 1), 256, 0, stream>>>(
        f1, w2T, tmp, 4096, 4096, 4096, 1024,
        0LL, 0LL, 0LL, 0LL, 0LL, 0LL, 1, b2 + e*CD, gates, e);

    // y += gate * LN(h + f2)
    ln_kernel<true><<<2048, 256, 0, stream>>>(h, tmp, g2 + e*CD, be2 + e*CD, nullptr, nullptr, y, gates, e);
  }

  epsfill<<<8192, 256, 0, stream>>>(y);
}

// Round 2
// 717.503 us; speedup vs baseline: 1.4722x; 1.4722x over previous
//
#include <hip/hip_runtime.h>
#include <hip/hip_bf16.h>

typedef __bf16 bf16;
typedef __attribute__((ext_vector_type(8))) __bf16 bf16x8;
typedef __attribute__((ext_vector_type(4))) float floatx4;

constexpr int CB = 8, CS = 256, CD = 1024, CH = 16, CE = 4, CFF = 4096, CHD = 64;
constexpr long long DD  = 1048576;     // D*D
constexpr long long DFF = 4194304;     // D*FF
constexpr long long BSD = 2097152;     // B*S*D

// ---------- fixed head of workspace (bytes) ----------
constexpr size_t OFF_XS    = 0;        // 8192 f
constexpr size_t OFF_CLEAN = 32768;    // 32 f
constexpr size_t OFF_RAW   = 32896;    // 32 f
constexpr size_t OFF_GATES = 33024;    // 32 f
constexpr size_t OFF_EACT  = 33152;    // 4 int
constexpr size_t OFF_XBF   = 33280;    // BSD bf16
constexpr size_t OFF_GREG  = OFF_XBF + (size_t)BSD*2;   // start of G-dependent region
// per-expert slab bytes: wT 4*DD*2 + w1T DFF*2 + w2T DFF*2 + arena 4*BSD*2 + P 4*BSD*2 + ao BSD*2 + h BSD*4 + hbf BSD*2
constexpr size_t PER_E = (size_t)4*DD*2 + 2*(size_t)DFF*2 + 2*(size_t)4*BSD*2 + (size_t)BSD*2 + (size_t)BSD*4 + (size_t)BSD*2;

// ---------- small kernels ----------
__global__ void zero_f(float* p) { p[blockIdx.x*256 + threadIdx.x] = 0.f; }

__global__ void epsfill(float* y) {
  int i = blockIdx.x*256 + threadIdx.x;
  if (y[i] == 0.f) y[i] = 2.2204460492503131e-16f;
}

__global__ void cvt_bf16(const float* __restrict__ in, bf16* __restrict__ out) {
  int i = blockIdx.x*256 + threadIdx.x; out[i] = (bf16)in[i];
}

// xs partials: part[chunk][8192], deterministic 2-stage
__global__ void xsum_part(const float* __restrict__ x, float* __restrict__ part) {
  int i = blockIdx.x*256 + threadIdx.x;   // 0..8191
  int chunk = blockIdx.y;                 // 0..7
  int b = i >> 10, d = i & 1023;
  float s = 0.f;
  for (int t = chunk*32; t < chunk*32 + 32; ++t) s += x[((long long)(b*CS + t))*CD + d];
  part[chunk*8192 + i] = s;
}
__global__ void xsum_combine(const float* __restrict__ part, float* __restrict__ xs) {
  int i = blockIdx.x*256 + threadIdx.x;
  float s = 0.f;
  for (int c = 0; c < 8; ++c) s += part[c*8192 + i];
  xs[i] = s;
}

__global__ __launch_bounds__(256)
void gate_dots(const float* __restrict__ xs, const float* __restrict__ wg,
               const float* __restrict__ wn, float* __restrict__ clean, float* __restrict__ raw) {
  int p = blockIdx.x, b = p >> 2, e = p & 3;
  int t = threadIdx.x;
  float s1 = 0.f, s2 = 0.f;
  for (int d = t; d < CD; d += 256) {
    float xv = xs[b*CD + d];
    s1 += xv * wg[d*CE + e];
    s2 += xv * wn[d*CE + e];
  }
  for (int off = 32; off; off >>= 1) { s1 += __shfl_xor(s1, off); s2 += __shfl_xor(s2, off); }
  __shared__ float r1[4], r2[4];
  int lane = t & 63, w = t >> 6;
  if (lane == 0) { r1[w] = s1; r2[w] = s2; }
  __syncthreads();
  if (t == 0) { clean[p] = r1[0]+r1[1]+r1[2]+r1[3]; raw[p] = r2[0]+r2[1]+r2[2]+r2[3]; }
}

__global__ void gating_kernel(const float* __restrict__ clean, const float* __restrict__ raw,
                              const float* __restrict__ noise, float* __restrict__ gates,
                              int* __restrict__ eact, float* __restrict__ loss_out) {
  if (threadIdx.x != 0) return;
  float imp[CE] = {0,0,0,0}, load[CE] = {0,0,0,0};
  int act[CE] = {0,0,0,0};
  for (int b = 0; b < CB; ++b) {
    float cl[CE], sd[CE], ny[CE];
    for (int e = 0; e < CE; ++e) {
      cl[e] = clean[b*CE + e];
      float rw = raw[b*CE + e];
      float sp = fmaxf(rw, 0.f) + log1pf(expf(-fabsf(rw)));   // stable softplus
      sd[e] = sp + 0.01f;
      ny[e] = cl[e] + noise[b*CE + e]*sd[e];
    }
    int idx[CE] = {0,1,2,3};
    for (int a = 0; a < 3; ++a) {
      int best = a;
      for (int c = a + 1; c < 4; ++c) if (ny[idx[c]] > ny[idx[best]]) best = c;
      int tt = idx[a]; idx[a] = idx[best]; idx[best] = tt;
    }
    float l0 = ny[idx[0]], l1 = ny[idx[1]], l2 = ny[idx[2]];
    float e1 = expf(l1 - l0);
    float g0 = 1.f/(1.f + e1), g1v = e1/(1.f + e1);
    for (int e = 0; e < CE; ++e) gates[b*CE + e] = 0.f;
    gates[b*CE + idx[0]] = g0; gates[b*CE + idx[1]] = g1v;
    imp[idx[0]] += g0; imp[idx[1]] += g1v;
    act[idx[0]] = 1; act[idx[1]] = 1;
    for (int e = 0; e < CE; ++e) {
      bool is_in = ny[e] > l2;
      float thr = is_in ? l2 : l1;
      float zz = (cl[e] - thr) / sd[e];
      load[e] += 0.5f * erfcf(-zz * 0.70710678118654752440f);
    }
  }
  float m1 = 0.f, m2 = 0.f;
  for (int e = 0; e < CE; ++e) { m1 += imp[e]; m2 += load[e]; }
  m1 *= 0.25f; m2 *= 0.25f;
  float v1 = 0.f, v2 = 0.f;
  for (int e = 0; e < CE; ++e) { float d1 = imp[e]-m1, d2 = load[e]-m2; v1 += d1*d1; v2 += d2*d2; }
  v1 *= (1.f/3.f); v2 *= (1.f/3.f);
  loss_out[0] = 0.01f * (v1/(m1*m1 + 1e-10f) + v2/(m2*m2 + 1e-10f));
  for (int e = 0; e < CE; ++e) eact[e] = act[e];
}

// transpose+convert: src fp32 (rows x cols) -> dst bf16 (cols x rows), z = g*nmat + mat
__global__ __launch_bounds__(256)
void transcvt(const float* __restrict__ s0, const float* __restrict__ s1,
              const float* __restrict__ s2, const float* __restrict__ s3,
              bf16* __restrict__ dst, int rows, int cols, int nmat, long long srcEStride,
              int e0, const int* __restrict__ eact) {
  int z = blockIdx.z; int mat = z % nmat; int g = z / nmat;
  if (eact[e0 + g] == 0) return;
  const float* src = ((mat == 0) ? s0 : (mat == 1) ? s1 : (mat == 2) ? s2 : s3)
                     + (long long)(e0 + g)*srcEStride;
  bf16* d = dst + (long long)z * rows * cols;
  __shared__ float tile[32][33];
  int c0 = blockIdx.x*32, r0 = blockIdx.y*32;
  int tx = threadIdx.x, ty = threadIdx.y;
#pragma unroll
  for (int i = 0; i < 4; ++i)
    tile[ty + 8*i][tx] = src[(long long)(r0 + ty + 8*i)*cols + c0 + tx];
  __syncthreads();
#pragma unroll
  for (int i = 0; i < 4; ++i)
    d[(long long)(c0 + ty + 8*i)*rows + r0 + tx] = (bf16)tile[tx][ty + 8*i];
}

// v (in arena[g] qkv slot 2, layout b,s,(h,hd)) -> vT (arena[g] slot 3, layout (b,h),hd,s)
__global__ __launch_bounds__(256)
void transpose_v(const bf16* __restrict__ arena, bf16* __restrict__ arena_w,
                 const float* __restrict__ gates, int e0) {
  int z = blockIdx.z; int h = z % CH; int b = (z/CH) % CB; int g = z/(CH*CB);
  if (gates[b*CE + e0 + g] == 0.f) return;
  const bf16* v = arena + (long long)g*4*BSD + 2*BSD;
  bf16* vt = arena_w + (long long)g*4*BSD + 3*BSD + (long long)(b*CH + h)*CHD*CS;
  __shared__ bf16 tile[32][33];
  int s0 = blockIdx.x*32, d0 = blockIdx.y*32;
  int tx = threadIdx.x, ty = threadIdx.y;
#pragma unroll
  for (int i = 0; i < 4; ++i)
    tile[ty + 8*i][tx] = v[((long long)(b*CS + s0 + ty + 8*i))*CD + h*CHD + d0 + tx];
  __syncthreads();
#pragma unroll
  for (int i = 0; i < 4; ++i)
    vt[(long long)(d0 + ty + 8*i)*CS + s0 + tx] = tile[tx][ty + 8*i];
}

// causal softmax, 4 q-rows per block (one per wave), in-place on bf16 scores
__global__ __launch_bounds__(256)
void softmax_causal(bf16* __restrict__ P, const float* __restrict__ gates, int e0, float scale) {
  int z = blockIdx.y;
  int b = (z / CH) % CB; int g = z / (CH*CB);
  if (gates[b*CE + e0 + g] == 0.f) return;
  int q = blockIdx.x*4 + (threadIdx.x >> 6);
  int t = threadIdx.x & 63;
  bf16* row = P + (long long)z*CS*CS + (long long)q*CS;
  float v[4];
#pragma unroll
  for (int i = 0; i < 4; ++i) {
    int k = t + 64*i;
    v[i] = (k <= q) ? (float)row[k]*scale : -3.0e38f;
  }
  float mx = fmaxf(fmaxf(v[0], v[1]), fmaxf(v[2], v[3]));
  for (int off = 32; off; off >>= 1) mx = fmaxf(mx, __shfl_xor(mx, off));
  float p[4], sum = 0.f;
#pragma unroll
  for (int i = 0; i < 4; ++i) { p[i] = __expf(v[i] - mx); sum += p[i]; }
  for (int off = 32; off; off >>= 1) sum += __shfl_xor(sum, off);
  float inv = 1.f / sum;
#pragma unroll
  for (int i = 0; i < 4; ++i) {
    int k = t + 64*i;
    row[k] = (bf16)((k <= q) ? p[i]*inv : 0.f);
  }
}

// layernorm over D of (a+b); ACC=false: write f32+bf16; ACC=true: y += gate*ln (atomic)
template<bool ACC>
__global__ __launch_bounds__(256)
void ln_kernel(const float* __restrict__ abase, long long aStride,
               const float* __restrict__ bbase, long long bStride,
               const float* __restrict__ gamma, const float* __restrict__ beta,
               float* __restrict__ outf, bf16* __restrict__ outbf,
               float* __restrict__ yacc, const float* __restrict__ gates, int e0) {
  int g = blockIdx.y;
  int row = blockIdx.x;
  int b = row >> 8;
  float gate = gates[b*CE + e0 + g];
  if (gate == 0.f) return;
  int t = threadIdx.x;
  const float* pa = abase + (long long)g*aStride + (long long)row*CD;
  const float* pb = bbase + (long long)g*bStride + (long long)row*CD;
  const float* gm = gamma + (long long)(e0 + g)*CD;
  const float* bt = beta  + (long long)(e0 + g)*CD;
  float v[4]; float s = 0.f, s2 = 0.f;
#pragma unroll
  for (int i = 0; i < 4; ++i) {
    int d = t + 256*i;
    float xv = pa[d] + pb[d];
    v[i] = xv; s += xv; s2 += xv*xv;
  }
  int lane = t & 63, wave = t >> 6;
  for (int off = 32; off; off >>= 1) { s += __shfl_xor(s, off); s2 += __shfl_xor(s2, off); }
  __shared__ float red[8];
  if (lane == 0) { red[wave*2] = s; red[wave*2 + 1] = s2; }
  __syncthreads();
  s  = red[0] + red[2] + red[4] + red[6];
  s2 = red[1] + red[3] + red[5] + red[7];
  float mean = s * (1.f/CD);
  float var  = s2 * (1.f/CD) - mean*mean;
  float rstd = rsqrtf(var + 1e-5f);
#pragma unroll
  for (int i = 0; i < 4; ++i) {
    int d = t + 256*i;
    float val = (v[i] - mean)*rstd*gm[d] + bt[d];
    if constexpr (ACC) unsafeAtomicAdd(&yacc[(long long)row*CD + d], gate*val);
    else {
      outf [(long long)g*BSD + (long long)row*CD + d] = val;
      outbf[(long long)g*BSD + (long long)row*CD + d] = (bf16)val;
    }
  }
}

// ---------- MFMA GEMM:  C[M,N] = A[M,K] * Bt[N,K]^T  (bf16, k-contiguous) ----------
// Staging via global_load_lds width=16. LDS slot (r,p) holds global k-chunk (p ^ (r&7))
// (XOR applied on the GLOBAL side since LDS dst is wave-uniform base + lane*16).
__device__ __forceinline__ void cp16(const bf16* g, bf16* l) {
  __builtin_amdgcn_global_load_lds((const __attribute__((address_space(1))) void*)g,
                                   (__attribute__((address_space(3))) void*)l, 16, 0, 0);
}

template<int R>
__device__ __forceinline__ void stage_tile_async(const bf16* __restrict__ src, int ld, bf16* dst) {
  int t = threadIdx.x;
  int l = t & 63, w = t >> 6;
  int rr = w*8 + (l >> 3);          // row within 32-row round
  int p  = l & 7;                   // LDS slot
#pragma unroll
  for (int i = 0; i < R/32; ++i) {
    int r = i*32 + rr;
    int c = p ^ (r & 7);            // global chunk for this slot (XOR self-inverse)
    cp16(src + (long long)r*ld + c*8, dst + (i*32 + w*8)*64);
  }
}

enum { EPI_BF16 = 0, EPI_F32 = 1, EPI_BRELU = 2, EPI_BIASF32 = 3 };

template<int BM, int BN, int EPI, bool CAUSAL, bool GATE_PAIR>
__global__ __launch_bounds__(256)
void gemm_nt(const bf16* __restrict__ A, const bf16* __restrict__ Bt, void* __restrict__ Cv,
             int K, int lda, int ldb, int ldc, int d1, int d2,
             long long oAe, long long oAb, long long oAr,
             long long oBe, long long oBb, long long oBr,
             long long oCe, long long oCb, long long oCr,
             const float* __restrict__ bias, long long biasStride,
             const float* __restrict__ gates, int e0) {
  int z = blockIdx.z;
  int zr = z % d1; int zt = z / d1; int zb = zt % d2; int ze = zt / d2;
  int m0 = blockIdx.x * BM, n0 = blockIdx.y * BN;   // x = M-tiles: consecutive blocks share B col-tile
  if (CAUSAL && n0 > m0) return;
  int gb = GATE_PAIR ? zb : (m0 / CS);
  if (gates[gb*CE + e0 + ze] == 0.f) return;
  A  += (long long)ze*oAe + (long long)zb*oAb + (long long)zr*oAr;
  Bt += (long long)ze*oBe + (long long)zb*oBb + (long long)zr*oBr;
  long long coff = (long long)ze*oCe + (long long)zb*oCb + (long long)zr*oCr;

  __shared__ bf16 As[BM*64];
  __shared__ bf16 Bs[BN*64];

  int wave = threadIdx.x >> 6;
  int lane = threadIdx.x & 63;
  constexpr int WN = BN/64;
  int wm = wave / WN, wn = wave % WN;
  int lr = lane & 15;
  int quad = lane >> 4;

  floatx4 acc[4][4] = {};

  for (int kt = 0; kt < K; kt += 64) {
    stage_tile_async<BM>(A  + (long long)m0*lda + kt, lda, As);
    stage_tile_async<BN>(Bt + (long long)n0*ldb + kt, ldb, Bs);
    __syncthreads();
#pragma unroll
    for (int kk = 0; kk < 2; ++kk) {
      bf16x8 af[4], bfr[4];
#pragma unroll
      for (int i = 0; i < 4; ++i) {
        int c = kk*4 + quad;
        int m = wm*64 + i*16 + lr;
        af[i]  = *(const bf16x8*)(As + m*64 + ((c ^ (m & 7))*8));
        int n = wn*64 + i*16 + lr;
        bfr[i] = *(const bf16x8*)(Bs + n*64 + ((c ^ (n & 7))*8));
      }
#pragma unroll
      for (int i = 0; i < 4; ++i)
#pragma unroll
        for (int j = 0; j < 4; ++j)
          acc[i][j] = __builtin_amdgcn_mfma_f32_16x16x32_bf16(af[i], bfr[j], acc[i][j], 0, 0, 0);
    }
    __syncthreads();
  }

#pragma unroll
  for (int j = 0; j < 4; ++j) {
    int col = n0 + wn*64 + j*16 + lr;
    float bv = 0.f;
    if constexpr (EPI == EPI_BRELU || EPI == EPI_BIASF32) bv = bias[(long long)ze*biasStride + col];
#pragma unroll
    for (int i = 0; i < 4; ++i) {
#pragma unroll
      for (int r = 0; r < 4; ++r) {
        int row = m0 + wm*64 + i*16 + quad*4 + r;
        float v = acc[i][j][r] + bv;
        long long idx = coff + (long long)row*ldc + col;
        if constexpr (EPI == EPI_BF16)        ((bf16*)Cv)[idx] = (bf16)v;
        else if constexpr (EPI == EPI_F32)    ((float*)Cv)[idx] = v;
        else if constexpr (EPI == EPI_BRELU)  ((bf16*)Cv)[idx] = (bf16)fmaxf(v, 0.f);
        else                                  ((float*)Cv)[idx] = v;
      }
    }
  }
}

// ---------- launch ----------
extern "C" void kernel_launch(void* const* d_in, const int* in_sizes, int n_in,
                              void* d_out, int out_size, void* d_ws, size_t ws_size,
                              hipStream_t stream) {
  const float* x       = (const float*)d_in[0];
  const float* noise   = (const float*)d_in[2];
  const float* w_gate  = (const float*)d_in[3];
  const float* w_noise = (const float*)d_in[4];
  const float* Wq      = (const float*)d_in[5];
  const float* Wk      = (const float*)d_in[6];
  const float* Wv      = (const float*)d_in[7];
  const float* Wo      = (const float*)d_in[8];
  const float* W1      = (const float*)d_in[9];
  const float* b1      = (const float*)d_in[10];
  const float* W2      = (const float*)d_in[11];
  const float* b2      = (const float*)d_in[12];
  const float* g1      = (const float*)d_in[13];
  const float* be1     = (const float*)d_in[14];
  const float* g2      = (const float*)d_in[15];
  const float* be2     = (const float*)d_in[16];

  char* ws = (char*)d_ws;
  float* y    = (float*)d_out;
  float* loss = y + (size_t)BSD;

  float* xs    = (float*)(ws + OFF_XS);
  float* clean = (float*)(ws + OFF_CLEAN);
  float* raw   = (float*)(ws + OFF_RAW);
  float* gates = (float*)(ws + OFF_GATES);
  int*   eact  = (int*)  (ws + OFF_EACT);
  bf16*  xbf   = (bf16*) (ws + OFF_XBF);

  // expert-group size chosen from ws_size (G=1 needs exactly round-1's footprint)
  int G = (ws_size >= OFF_GREG + 4*PER_E) ? 4 : (ws_size >= OFF_GREG + 2*PER_E) ? 2 : 1;

  char* p = ws + OFF_GREG;
  bf16* wT    = (bf16*)p;  p += (size_t)G*4*DD*2;
  bf16* w1T   = (bf16*)p;  p += (size_t)G*DFF*2;
  bf16* w2T   = (bf16*)p;  p += (size_t)G*DFF*2;
  bf16* arena = (bf16*)p;  p += (size_t)G*4*BSD*2;   // per g: qkv(3*BSD)+vT(BSD), later f1(4*BSD)
  bf16* Pb    = (bf16*)p;  p += (size_t)G*4*BSD*2;   // per g: P bf16 (4*BSD); tmp f32 aliases (2*BSD f32)
  bf16* ao    = (bf16*)p;  p += (size_t)G*BSD*2;
  float* h    = (float*)p; p += (size_t)G*BSD*4;
  bf16* hbf   = (bf16*)p;  p += (size_t)G*BSD*2;
  float* tmp  = (float*)Pb;                           // per g stride 2*BSD f32 elems
  float* part = (float*)(ws + OFF_GREG);              // 8x8192 f, pre-expert lifetime only

  zero_f<<<8192, 256, 0, stream>>>(y);
  xsum_part<<<dim3(32, 8), 256, 0, stream>>>(x, part);
  xsum_combine<<<32, 256, 0, stream>>>(part, xs);
  gate_dots<<<32, 256, 0, stream>>>(xs, w_gate, w_noise, clean, raw);
  gating_kernel<<<1, 64, 0, stream>>>(clean, raw, noise, gates, eact, loss);
  cvt_bf16<<<8192, 256, 0, stream>>>(x, xbf);

  for (int e0 = 0; e0 < CE; e0 += G) {
    // weight transpose+convert (per-expert gated by eact)
    transcvt<<<dim3(32, 32, G*4), dim3(32, 8), 0, stream>>>(Wq, Wk, Wv, Wo, wT, 1024, 1024, 4, DD, e0, eact);
    transcvt<<<dim3(128, 32, G), dim3(32, 8), 0, stream>>>(W1, W1, W1, W1, w1T, 1024, 4096, 1, DFF, e0, eact);
    transcvt<<<dim3(32, 128, G), dim3(32, 8), 0, stream>>>(W2, W2, W2, W2, w2T, 4096, 1024, 1, DFF, e0, eact);

    // q,k,v = x @ {Wq,Wk,Wv}  : z = g*3 + mat
    gemm_nt<128, 128, EPI_BF16, false, false><<<dim3(16, 8, G*3), 256, 0, stream>>>(
        xbf, wT, arena, 1024, 1024, 1024, 1024,
        3, 1,
        0, 0, 0,
        4*DD, 0, DD,
        4*BSD, 0, BSD,
        nullptr, 0, gates, e0);

    transpose_v<<<dim3(8, 2, G*CB*CH), dim3(32, 8), 0, stream>>>(arena, arena, gates, e0);

    // scores = q @ k^T : z = (g*CB + b)*CH + h
    gemm_nt<128, 128, EPI_BF16, true, true><<<dim3(2, 2, G*CB*CH), 256, 0, stream>>>(
        arena, arena + BSD, Pb, 64, 1024, 1024, 256,
        CH, CB,
        4*BSD, (long long)CS*CD, CHD,
        4*BSD, (long long)CS*CD, CHD,
        4*BSD, (long long)CH*CS*CS, (long long)CS*CS,
        nullptr, 0, gates, e0);

    softmax_causal<<<dim3(CS/4, G*CB*CH), 256, 0, stream>>>(Pb, gates, e0, 0.125f);

    // ao = P @ v
    gemm_nt<256, 64, EPI_BF16, false, true><<<dim3(1, 1, G*CB*CH), 256, 0, stream>>>(
        Pb, arena + 3*BSD, ao, 256, 256, 256, 1024,
        CH, CB,
        4*BSD, (long long)CH*CS*CS, (long long)CS*CS,
        4*BSD, (long long)CH*CHD*CS, (long long)CHD*CS,
        BSD, (long long)CS*CD, CHD,
        nullptr, 0, gates, e0);

    // o = ao @ Wo -> tmp (f32)
    gemm_nt<128, 128, EPI_F32, false, false><<<dim3(16, 8, G), 256, 0, stream>>>(
        ao, wT + 3*DD, tmp, 1024, 1024, 1024, 1024,
        1, 1,
        BSD, 0, 0,
        4*DD, 0, 0,
        2*BSD, 0, 0,
        nullptr, 0, gates, e0);

    // h = LN(x + o)
    ln_kernel<false><<<dim3(2048, G), 256, 0, stream>>>(
        x, 0, tmp, 2*BSD, g1, be1, h, hbf, nullptr, gates, e0);

    // f1 = relu(h @ W1 + b1)  (f1 overlays arena)
    gemm_nt<128, 128, EPI_BRELU, false, false><<<dim3(16, 32, G), 256, 0, stream>>>(
        hbf, w1T, arena, 1024, 1024, 1024, 4096,
        1, 1,
        BSD, 0, 0,
        DFF, 0, 0,
        4*BSD, 0, 0,
        b1 + (long long)e0*CFF, CFF, gates, e0);

    // f2 = f1 @ W2 + b2 -> tmp (f32)
    gemm_nt<128, 128, EPI_BIASF32, false, false><<<dim3(16, 8, G), 256, 0, stream>>>(
        arena, w2T, tmp, 4096, 4096, 4096, 1024,
        1, 1,
        4*BSD, 0, 0,
        DFF, 0, 0,
        2*BSD, 0, 0,
        b2 + (long long)e0*CD, CD, gates, e0);

    // y += gate * LN(h + f2)
    ln_kernel<true><<<dim3(2048, G), 256, 0, stream>>>(
        h, BSD, tmp, 2*BSD, g2, be2, nullptr, nullptr, y, gates, e0);
  }

  epsfill<<<8192, 256, 0, stream>>>(y);
}

// Round 3
// 636.427 us; speedup vs baseline: 1.6598x; 1.1274x over previous
//
#include <hip/hip_runtime.h>
#include <hip/hip_bf16.h>

typedef __bf16 bf16;
typedef __attribute__((ext_vector_type(4))) __bf16 bf16x4;
typedef __attribute__((ext_vector_type(8))) __bf16 bf16x8;
typedef __attribute__((ext_vector_type(4))) float floatx4;

constexpr int CB = 8, CS = 256, CD = 1024, CH = 16, CE = 4, CFF = 4096, CHD = 64;
constexpr long long DD  = 1048576;     // D*D
constexpr long long DFF = 4194304;     // D*FF
constexpr long long BSD = 2097152;     // B*S*D

// ---------- fixed head of workspace (bytes) ----------
constexpr size_t OFF_XS    = 0;        // 8192 f
constexpr size_t OFF_CLEAN = 32768;    // 32 f
constexpr size_t OFF_RAW   = 32896;    // 32 f
constexpr size_t OFF_GATES = 33024;    // 32 f
constexpr size_t OFF_EACT  = 33152;    // 4 int
constexpr size_t OFF_XBF   = 33280;    // BSD bf16
constexpr size_t OFF_GREG  = OFF_XBF + (size_t)BSD*2;   // start of G-dependent region
// per-expert slab: wT 4*DD*2 + w1T DFF*2 + w2T DFF*2 + arena 4*BSD*2 + Pb 4*BSD*2 + ao BSD*2 + h BSD*4 + hbf BSD*2
constexpr size_t PER_E = (size_t)4*DD*2 + 2*(size_t)DFF*2 + 2*(size_t)4*BSD*2 + (size_t)BSD*2 + (size_t)BSD*4 + (size_t)BSD*2;

// ---------- small kernels ----------
__global__ void zero_f(float* p) { p[blockIdx.x*256 + threadIdx.x] = 0.f; }

__global__ void epsfill(float* y) {
  int i = blockIdx.x*256 + threadIdx.x;
  if (y[i] == 0.f) y[i] = 2.2204460492503131e-16f;
}

__global__ void cvt_bf16(const float* __restrict__ in, bf16* __restrict__ out) {
  int i = blockIdx.x*256 + threadIdx.x;
  float4 v = ((const float4*)in)[i];
  bf16x4 o; o[0] = (bf16)v.x; o[1] = (bf16)v.y; o[2] = (bf16)v.z; o[3] = (bf16)v.w;
  ((bf16x4*)out)[i] = o;
}

// xs partials: part[chunk][8192], deterministic 2-stage
__global__ void xsum_part(const float* __restrict__ x, float* __restrict__ part) {
  int i = blockIdx.x*256 + threadIdx.x;   // 0..8191
  int chunk = blockIdx.y;                 // 0..7
  int b = i >> 10, d = i & 1023;
  float s = 0.f;
  for (int t = chunk*32; t < chunk*32 + 32; ++t) s += x[((long long)(b*CS + t))*CD + d];
  part[chunk*8192 + i] = s;
}
__global__ void xsum_combine(const float* __restrict__ part, float* __restrict__ xs) {
  int i = blockIdx.x*256 + threadIdx.x;
  float s = 0.f;
  for (int c = 0; c < 8; ++c) s += part[c*8192 + i];
  xs[i] = s;
}

__global__ __launch_bounds__(256)
void gate_dots(const float* __restrict__ xs, const float* __restrict__ wg,
               const float* __restrict__ wn, float* __restrict__ clean, float* __restrict__ raw) {
  int p = blockIdx.x, b = p >> 2, e = p & 3;
  int t = threadIdx.x;
  float s1 = 0.f, s2 = 0.f;
  for (int d = t; d < CD; d += 256) {
    float xv = xs[b*CD + d];
    s1 += xv * wg[d*CE + e];
    s2 += xv * wn[d*CE + e];
  }
  for (int off = 32; off; off >>= 1) { s1 += __shfl_xor(s1, off); s2 += __shfl_xor(s2, off); }
  __shared__ float r1[4], r2[4];
  int lane = t & 63, w = t >> 6;
  if (lane == 0) { r1[w] = s1; r2[w] = s2; }
  __syncthreads();
  if (t == 0) { clean[p] = r1[0]+r1[1]+r1[2]+r1[3]; raw[p] = r2[0]+r2[1]+r2[2]+r2[3]; }
}

__global__ void gating_kernel(const float* __restrict__ clean, const float* __restrict__ raw,
                              const float* __restrict__ noise, float* __restrict__ gates,
                              int* __restrict__ eact, float* __restrict__ loss_out) {
  if (threadIdx.x != 0) return;
  float imp[CE] = {0,0,0,0}, load[CE] = {0,0,0,0};
  int act[CE] = {0,0,0,0};
  for (int b = 0; b < CB; ++b) {
    float cl[CE], sd[CE], ny[CE];
    for (int e = 0; e < CE; ++e) {
      cl[e] = clean[b*CE + e];
      float rw = raw[b*CE + e];
      float sp = fmaxf(rw, 0.f) + log1pf(expf(-fabsf(rw)));   // stable softplus
      sd[e] = sp + 0.01f;
      ny[e] = cl[e] + noise[b*CE + e]*sd[e];
    }
    int idx[CE] = {0,1,2,3};
    for (int a = 0; a < 3; ++a) {
      int best = a;
      for (int c = a + 1; c < 4; ++c) if (ny[idx[c]] > ny[idx[best]]) best = c;
      int tt = idx[a]; idx[a] = idx[best]; idx[best] = tt;
    }
    float l0 = ny[idx[0]], l1 = ny[idx[1]], l2 = ny[idx[2]];
    float e1 = expf(l1 - l0);
    float g0 = 1.f/(1.f + e1), g1v = e1/(1.f + e1);
    for (int e = 0; e < CE; ++e) gates[b*CE + e] = 0.f;
    gates[b*CE + idx[0]] = g0; gates[b*CE + idx[1]] = g1v;
    imp[idx[0]] += g0; imp[idx[1]] += g1v;
    act[idx[0]] = 1; act[idx[1]] = 1;
    for (int e = 0; e < CE; ++e) {
      bool is_in = ny[e] > l2;
      float thr = is_in ? l2 : l1;
      float zz = (cl[e] - thr) / sd[e];
      load[e] += 0.5f * erfcf(-zz * 0.70710678118654752440f);
    }
  }
  float m1 = 0.f, m2 = 0.f;
  for (int e = 0; e < CE; ++e) { m1 += imp[e]; m2 += load[e]; }
  m1 *= 0.25f; m2 *= 0.25f;
  float v1 = 0.f, v2 = 0.f;
  for (int e = 0; e < CE; ++e) { float d1 = imp[e]-m1, d2 = load[e]-m2; v1 += d1*d1; v2 += d2*d2; }
  v1 *= (1.f/3.f); v2 *= (1.f/3.f);
  loss_out[0] = 0.01f * (v1/(m1*m1 + 1e-10f) + v2/(m2*m2 + 1e-10f));
  for (int e = 0; e < CE; ++e) eact[e] = act[e];
}

// transpose+convert: src fp32 (rows x cols) -> dst bf16 (cols x rows), z = g*nmat + mat
// tile: 64 src rows x 32 src cols; packed dword stores on the dst side.
__global__ __launch_bounds__(256)
void transcvt(const float* __restrict__ s0, const float* __restrict__ s1,
              const float* __restrict__ s2, const float* __restrict__ s3,
              bf16* __restrict__ dst, int rows, int cols, int nmat, long long srcEStride,
              int e0, const int* __restrict__ eact) {
  int z = blockIdx.z; int mat = z % nmat; int g = z / nmat;
  if (eact[e0 + g] == 0) return;
  const float* src = ((mat == 0) ? s0 : (mat == 1) ? s1 : (mat == 2) ? s2 : s3)
                     + (long long)(e0 + g)*srcEStride;
  bf16* d = dst + (long long)z * rows * cols;
  __shared__ float tile[64][33];
  int c0 = blockIdx.x*32, r0 = blockIdx.y*64;
  int t = threadIdx.x;
#pragma unroll
  for (int i = 0; i < 8; ++i) {
    int id = i*256 + t; int r = id >> 5, c = id & 31;
    tile[r][c] = src[(long long)(r0 + r)*cols + c0 + c];
  }
  __syncthreads();
  unsigned* dw = (unsigned*)d;
#pragma unroll
  for (int i = 0; i < 4; ++i) {
    int id = i*256 + t; int dr = id >> 5, c = id & 31;
    bf16x4 pk4; // pack two bf16 into one dword
    bf16 v0 = (bf16)tile[2*c][dr], v1 = (bf16)tile[2*c + 1][dr];
    union { bf16 h[2]; unsigned u; } pk; pk.h[0] = v0; pk.h[1] = v1;
    dw[((long long)(c0 + dr)*rows + r0)/2 + c] = pk.u;
    (void)pk4;
  }
}

// v (arena[g] slot 2, layout b,s,(h,hd)) -> vT (arena[g] slot 3, layout (b,h),hd,s)
__global__ __launch_bounds__(256)
void transpose_v(const bf16* __restrict__ arena, bf16* __restrict__ arena_w,
                 const float* __restrict__ gates, int e0) {
  int z = blockIdx.z; int h = z % CH; int b = (z/CH) % CB; int g = z/(CH*CB);
  if (gates[b*CE + e0 + g] == 0.f) return;
  const bf16* v = arena + (long long)g*4*BSD + 2*BSD;
  bf16* vt = arena_w + (long long)g*4*BSD + 3*BSD + (long long)(b*CH + h)*CHD*CS;
  __shared__ bf16 tile[32][33];
  int s0 = blockIdx.x*32, d0 = blockIdx.y*32;
  int tx = threadIdx.x % 32, ty = threadIdx.x / 32;
#pragma unroll
  for (int i = 0; i < 4; ++i)
    tile[ty + 8*i][tx] = v[((long long)(b*CS + s0 + ty + 8*i))*CD + h*CHD + d0 + tx];
  __syncthreads();
#pragma unroll
  for (int i = 0; i < 4; ++i)
    vt[(long long)(d0 + ty + 8*i)*CS + s0 + tx] = tile[tx][ty + 8*i];
}

// ---------- async staging (global_load_lds width=16, XOR-swizzled on the global side) ----------
__device__ __forceinline__ void cp16(const bf16* g, bf16* l) {
  __builtin_amdgcn_global_load_lds((const __attribute__((address_space(1))) void*)g,
                                   (__attribute__((address_space(3))) void*)l, 16, 0, 0);
}

template<int R, int W>
__device__ __forceinline__ void stage(const bf16* __restrict__ src, int ld, bf16* dst) {
  constexpr int W8 = W/8;
  int t = threadIdx.x;
  int l = t & 63, wid = t >> 6;
#pragma unroll
  for (int i = 0; i < (R*W8)/256; ++i) {
    int idb = i*256 + wid*64;         // wave-uniform LDS base (chunk units)
    int id = idb + l;
    int row = id / W8, sl = id % W8;
    int gc = sl ^ (row & 7);          // XOR self-inverse; stays in low 3 bits
    cp16(src + (long long)row*ld + gc*8, dst + (long long)idb*8);
  }
}

// ---------- fused flash attention: per (g,b,h) block ----------
// S = Q K^T * scale (causal), softmax fp32, O = P V. Q/K/V^T fragments from global.
__global__ __launch_bounds__(256)
void attn_fused(const bf16* __restrict__ arena, bf16* __restrict__ ao,
                const float* __restrict__ gates, int e0) {
  int z = blockIdx.x;
  int h = z % CH, b = (z/CH) % CB, g = z/(CH*CB);
  if (gates[b*CE + e0 + g] == 0.f) return;
  const bf16* qp = arena + (long long)g*4*BSD + (long long)(b*CS)*CD + h*CHD;
  const bf16* kp = qp + BSD;
  const bf16* vt = arena + (long long)g*4*BSD + 3*BSD + (long long)(b*CH + h)*CHD*CS;
  bf16* aop = ao + (long long)g*BSD + (long long)(b*CS)*CD + h*CHD;

  __shared__ bf16 Ps[64*264];            // P tile, padded stride 264 -> 2-way banks
  __shared__ float smaxL[64*4], ssumL[64*4], Lrow[64];

  int t = threadIdx.x, w = t >> 6, lane = t & 63, lr = lane & 15, quad = lane >> 4;

  for (int qt = 0; qt < 4; ++qt) {
    // ---- S = Q Kt : wave w covers key cols w*64..w*64+63
    floatx4 accs[4][4] = {};
#pragma unroll
    for (int kk = 0; kk < 2; ++kk) {
      int c = kk*4 + quad;
      bf16x8 af[4], bfr[4];
#pragma unroll
      for (int i = 0; i < 4; ++i) {
        af[i]  = *(const bf16x8*)(qp + (long long)(qt*64 + i*16 + lr)*CD + c*8);
        bfr[i] = *(const bf16x8*)(kp + (long long)(w*64  + i*16 + lr)*CD + c*8);
      }
#pragma unroll
      for (int i = 0; i < 4; ++i)
#pragma unroll
        for (int j = 0; j < 4; ++j)
          accs[i][j] = __builtin_amdgcn_mfma_f32_16x16x32_bf16(af[i], bfr[j], accs[i][j], 0, 0, 0);
    }
    // ---- scale + causal mask + row max (rows m = i*16+quad*4+r, cols n = w*64+j*16+lr)
    float rmax[4][4];
#pragma unroll
    for (int i = 0; i < 4; ++i)
#pragma unroll
      for (int r = 0; r < 4; ++r) {
        int qrow = qt*64 + i*16 + quad*4 + r;
        float m = -3.0e38f;
#pragma unroll
        for (int j = 0; j < 4; ++j) {
          int kcol = w*64 + j*16 + lr;
          float s = accs[i][j][r]*0.125f;
          s = (kcol <= qrow) ? s : -3.0e38f;
          accs[i][j][r] = s;
          m = fmaxf(m, s);
        }
        rmax[i][r] = m;
      }
#pragma unroll
    for (int off = 1; off <= 8; off <<= 1)
#pragma unroll
      for (int i = 0; i < 4; ++i)
#pragma unroll
        for (int r = 0; r < 4; ++r) rmax[i][r] = fmaxf(rmax[i][r], __shfl_xor(rmax[i][r], off));
    if (lr == 0)
#pragma unroll
      for (int i = 0; i < 4; ++i)
#pragma unroll
        for (int r = 0; r < 4; ++r) smaxL[(i*16 + quad*4 + r)*4 + w] = rmax[i][r];
    __syncthreads();
    // ---- exp + row sum
    float rsum[4][4];
#pragma unroll
    for (int i = 0; i < 4; ++i)
#pragma unroll
      for (int r = 0; r < 4; ++r) {
        floatx4 mv = *(const floatx4*)&smaxL[(i*16 + quad*4 + r)*4];
        float M = fmaxf(fmaxf(mv[0], mv[1]), fmaxf(mv[2], mv[3]));
        float srow = 0.f;
#pragma unroll
        for (int j = 0; j < 4; ++j) {
          float p = __expf(accs[i][j][r] - M);
          accs[i][j][r] = p;
          srow += p;
        }
        rsum[i][r] = srow;
      }
#pragma unroll
    for (int off = 1; off <= 8; off <<= 1)
#pragma unroll
      for (int i = 0; i < 4; ++i)
#pragma unroll
        for (int r = 0; r < 4; ++r) rsum[i][r] += __shfl_xor(rsum[i][r], off);
    if (lr == 0)
#pragma unroll
      for (int i = 0; i < 4; ++i)
#pragma unroll
        for (int r = 0; r < 4; ++r) ssumL[(i*16 + quad*4 + r)*4 + w] = rsum[i][r];
    __syncthreads();
    if (w == 0 && lr == 0) {
#pragma unroll
      for (int i = 0; i < 4; ++i)
#pragma unroll
        for (int r = 0; r < 4; ++r) {
          int m = i*16 + quad*4 + r;
          floatx4 sv = *(const floatx4*)&ssumL[m*4];
          Lrow[m] = sv[0] + sv[1] + sv[2] + sv[3];
        }
    }
    // ---- P -> LDS (unnormalized, bf16)
#pragma unroll
    for (int i = 0; i < 4; ++i)
#pragma unroll
      for (int j = 0; j < 4; ++j)
#pragma unroll
        for (int r = 0; r < 4; ++r)
          Ps[(i*16 + quad*4 + r)*264 + w*64 + j*16 + lr] = (bf16)accs[i][j][r];
    __syncthreads();
    // ---- O = P V : wave w owns O rows w*16..w*16+15, full K=256
    floatx4 acco[4] = {};
#pragma unroll
    for (int ks = 0; ks < 8; ++ks) {
      int c = ks*4 + quad;
      bf16x8 ap = *(const bf16x8*)(Ps + (w*16 + lr)*264 + c*8);
#pragma unroll
      for (int j = 0; j < 4; ++j) {
        bf16x8 bv = *(const bf16x8*)(vt + (long long)(j*16 + lr)*CS + c*8);
        acco[j] = __builtin_amdgcn_mfma_f32_16x16x32_bf16(ap, bv, acco[j], 0, 0, 0);
      }
    }
#pragma unroll
    for (int r = 0; r < 4; ++r) {
      int orow = w*16 + quad*4 + r;
      float inv = 1.f / Lrow[orow];
#pragma unroll
      for (int j = 0; j < 4; ++j)
        aop[(long long)(qt*64 + orow)*CD + j*16 + lr] = (bf16)(acco[j][r]*inv);
    }
  }
}

// ---------- layernorms ----------
// h = LN(x + Wo-partial0 + Wo-partial1), writes f32 + bf16
__global__ __launch_bounds__(256)
void ln1_kernel(const float* __restrict__ x, const float* __restrict__ PbF,
                const float* __restrict__ gamma, const float* __restrict__ beta,
                float* __restrict__ h, bf16* __restrict__ hbf,
                const float* __restrict__ gates, int e0, int G) {
  int g = blockIdx.y, row = blockIdx.x, b = row >> 8;
  if (gates[b*CE + e0 + g] == 0.f) return;
  int t = threadIdx.x;
  const float* pa = x + (long long)row*CD;
  const float* p0 = PbF + ((long long)g)*BSD + (long long)row*CD;
  const float* p1 = PbF + ((long long)(G + g))*BSD + (long long)row*CD;
  const float* gm = gamma + (long long)(e0 + g)*CD;
  const float* bt = beta  + (long long)(e0 + g)*CD;
  float v[4]; float s = 0.f, s2 = 0.f;
#pragma unroll
  for (int i = 0; i < 4; ++i) {
    int d = t + 256*i;
    float xv = pa[d] + p0[d] + p1[d];
    v[i] = xv; s += xv; s2 += xv*xv;
  }
  int lane = t & 63, wave = t >> 6;
  for (int off = 32; off; off >>= 1) { s += __shfl_xor(s, off); s2 += __shfl_xor(s2, off); }
  __shared__ float red[8];
  if (lane == 0) { red[wave*2] = s; red[wave*2 + 1] = s2; }
  __syncthreads();
  s  = red[0] + red[2] + red[4] + red[6];
  s2 = red[1] + red[3] + red[5] + red[7];
  float mean = s * (1.f/CD);
  float var  = s2 * (1.f/CD) - mean*mean;
  float rstd = rsqrtf(var + 1e-5f);
#pragma unroll
  for (int i = 0; i < 4; ++i) {
    int d = t + 256*i;
    float val = (v[i] - mean)*rstd*gm[d] + bt[d];
    h  [(long long)g*BSD + (long long)row*CD + d] = val;
    hbf[(long long)g*BSD + (long long)row*CD + d] = (bf16)val;
  }
}

// y += gate * LN(h + sum of 4 bf16 FF2-partials)
__global__ __launch_bounds__(256)
void ln2_kernel(const float* __restrict__ h, const bf16* __restrict__ PbB,
                const float* __restrict__ gamma, const float* __restrict__ beta,
                float* __restrict__ y, const float* __restrict__ gates, int e0, int G) {
  int g = blockIdx.y, row = blockIdx.x, b = row >> 8;
  float gate = gates[b*CE + e0 + g];
  if (gate == 0.f) return;
  int t = threadIdx.x;
  const float* ph = h + (long long)g*BSD + (long long)row*CD;
  const float* gm = gamma + (long long)(e0 + g)*CD;
  const float* bt = beta  + (long long)(e0 + g)*CD;
  float v[4]; float s = 0.f, s2 = 0.f;
#pragma unroll
  for (int i = 0; i < 4; ++i) {
    int d = t + 256*i;
    float xv = ph[d];
#pragma unroll
    for (int p = 0; p < 4; ++p)
      xv += (float)PbB[((long long)(p*G + g))*BSD + (long long)row*CD + d];
    v[i] = xv; s += xv; s2 += xv*xv;
  }
  int lane = t & 63, wave = t >> 6;
  for (int off = 32; off; off >>= 1) { s += __shfl_xor(s, off); s2 += __shfl_xor(s2, off); }
  __shared__ float red[8];
  if (lane == 0) { red[wave*2] = s; red[wave*2 + 1] = s2; }
  __syncthreads();
  s  = red[0] + red[2] + red[4] + red[6];
  s2 = red[1] + red[3] + red[5] + red[7];
  float mean = s * (1.f/CD);
  float var  = s2 * (1.f/CD) - mean*mean;
  float rstd = rsqrtf(var + 1e-5f);
#pragma unroll
  for (int i = 0; i < 4; ++i) {
    int d = t + 256*i;
    float val = (v[i] - mean)*rstd*gm[d] + bt[d];
    unsafeAtomicAdd(&y[(long long)row*CD + d], gate*val);
  }
}

// ---------- MFMA GEMM:  C[M,N] = A[M,K] * Bt[N,K]^T  (bf16, k-contiguous), optional split-K ----------
enum { EPI_BF16 = 0, EPI_F32 = 1, EPI_BRELU = 2, EPI_BIASBF16 = 3 };

template<int BM, int BN, int EPI, int KS>
__global__ __launch_bounds__(256)
void gemm_nt(const bf16* __restrict__ A, const bf16* __restrict__ Bt, void* __restrict__ Cv,
             int K /*per split*/, int lda, int ldb, int ldc, int d1, int d2,
             long long oAe, long long oAb, long long oAr,
             long long oBe, long long oBb, long long oBr,
             long long oCe, long long oCb, long long oCr, long long oCk,
             const float* __restrict__ bias, long long biasStride,
             const float* __restrict__ gates, int e0) {
  int z = blockIdx.z;
  int zk = z % KS; int zz = z / KS;
  int zr = zz % d1; int zt = zz / d1; int zb = zt % d2; int ze = zt / d2;
  int m0 = blockIdx.x * BM, n0 = blockIdx.y * BN;
  if (gates[(m0/CS)*CE + e0 + ze] == 0.f) return;
  A  += (long long)ze*oAe + (long long)zb*oAb + (long long)zr*oAr + (long long)zk*K;
  Bt += (long long)ze*oBe + (long long)zb*oBb + (long long)zr*oBr + (long long)zk*K;
  long long coff = (long long)ze*oCe + (long long)zb*oCb + (long long)zr*oCr + (long long)zk*oCk;

  __shared__ bf16 As[BM*64];
  __shared__ bf16 Bs[BN*64];

  int wave = threadIdx.x >> 6;
  int lane = threadIdx.x & 63;
  constexpr int WN = BN/64;
  int wm = wave / WN, wn = wave % WN;
  int lr = lane & 15;
  int quad = lane >> 4;

  floatx4 acc[4][4] = {};

  for (int kt = 0; kt < K; kt += 64) {
    stage<BM, 64>(A  + (long long)m0*lda + kt, lda, As);
    stage<BN, 64>(Bt + (long long)n0*ldb + kt, ldb, Bs);
    __syncthreads();
#pragma unroll
    for (int kk = 0; kk < 2; ++kk) {
      bf16x8 af[4], bfr[4];
#pragma unroll
      for (int i = 0; i < 4; ++i) {
        int c = kk*4 + quad;
        int m = wm*64 + i*16 + lr;
        af[i]  = *(const bf16x8*)(As + m*64 + ((c ^ (m & 7))*8));
        int n = wn*64 + i*16 + lr;
        bfr[i] = *(const bf16x8*)(Bs + n*64 + ((c ^ (n & 7))*8));
      }
#pragma unroll
      for (int i = 0; i < 4; ++i)
#pragma unroll
        for (int j = 0; j < 4; ++j)
          acc[i][j] = __builtin_amdgcn_mfma_f32_16x16x32_bf16(af[i], bfr[j], acc[i][j], 0, 0, 0);
    }
    __syncthreads();
  }

#pragma unroll
  for (int j = 0; j < 4; ++j) {
    int col = n0 + wn*64 + j*16 + lr;
    float bv = 0.f;
    if constexpr (EPI == EPI_BRELU || EPI == EPI_BIASBF16)
      if (zk == 0) bv = bias[(long long)ze*biasStride + col];
#pragma unroll
    for (int i = 0; i < 4; ++i) {
#pragma unroll
      for (int r = 0; r < 4; ++r) {
        int row = m0 + wm*64 + i*16 + quad*4 + r;
        float v = acc[i][j][r] + bv;
        long long idx = coff + (long long)row*ldc + col;
        if constexpr (EPI == EPI_BF16)          ((bf16*)Cv)[idx] = (bf16)v;
        else if constexpr (EPI == EPI_F32)      ((float*)Cv)[idx] = v;
        else if constexpr (EPI == EPI_BRELU)    ((bf16*)Cv)[idx] = (bf16)fmaxf(v, 0.f);
        else                                    ((bf16*)Cv)[idx] = (bf16)v;
      }
    }
  }
}

// ---------- launch ----------
extern "C" void kernel_launch(void* const* d_in, const int* in_sizes, int n_in,
                              void* d_out, int out_size, void* d_ws, size_t ws_size,
                              hipStream_t stream) {
  const float* x       = (const float*)d_in[0];
  const float* noise   = (const float*)d_in[2];
  const float* w_gate  = (const float*)d_in[3];
  const float* w_noise = (const float*)d_in[4];
  const float* Wq      = (const float*)d_in[5];
  const float* Wk      = (const float*)d_in[6];
  const float* Wv      = (const float*)d_in[7];
  const float* Wo      = (const float*)d_in[8];
  const float* W1      = (const float*)d_in[9];
  const float* b1      = (const float*)d_in[10];
  const float* W2      = (const float*)d_in[11];
  const float* b2      = (const float*)d_in[12];
  const float* g1      = (const float*)d_in[13];
  const float* be1     = (const float*)d_in[14];
  const float* g2      = (const float*)d_in[15];
  const float* be2     = (const float*)d_in[16];

  char* ws = (char*)d_ws;
  float* y    = (float*)d_out;
  float* loss = y + (size_t)BSD;

  float* xs    = (float*)(ws + OFF_XS);
  float* clean = (float*)(ws + OFF_CLEAN);
  float* raw   = (float*)(ws + OFF_RAW);
  float* gates = (float*)(ws + OFF_GATES);
  int*   eact  = (int*)  (ws + OFF_EACT);
  bf16*  xbf   = (bf16*) (ws + OFF_XBF);

  int G = (ws_size >= OFF_GREG + 4*PER_E) ? 4 : (ws_size >= OFF_GREG + 2*PER_E) ? 2 : 1;

  char* p = ws + OFF_GREG;
  bf16* wT    = (bf16*)p;  p += (size_t)G*4*DD*2;
  bf16* w1T   = (bf16*)p;  p += (size_t)G*DFF*2;
  bf16* w2T   = (bf16*)p;  p += (size_t)G*DFF*2;
  bf16* arena = (bf16*)p;  p += (size_t)G*4*BSD*2;   // per g: qkv(3*BSD)+vT(BSD); later f1(4*BSD)
  char* Pb    = p;         p += (size_t)G*4*BSD*2;   // Wo: 2 f32 partials; FF2: 4 bf16 partials
  bf16* ao    = (bf16*)p;  p += (size_t)G*BSD*2;
  float* h    = (float*)p; p += (size_t)G*BSD*4;
  bf16* hbf   = (bf16*)p;  p += (size_t)G*BSD*2;
  float* PbF  = (float*)Pb;
  bf16*  PbB  = (bf16*)Pb;
  float* part = (float*)(ws + OFF_GREG);             // 8x8192 f, pre-expert lifetime only

  zero_f<<<8192, 256, 0, stream>>>(y);
  xsum_part<<<dim3(32, 8), 256, 0, stream>>>(x, part);
  xsum_combine<<<32, 256, 0, stream>>>(part, xs);
  gate_dots<<<32, 256, 0, stream>>>(xs, w_gate, w_noise, clean, raw);
  gating_kernel<<<1, 64, 0, stream>>>(clean, raw, noise, gates, eact, loss);
  cvt_bf16<<<2048, 256, 0, stream>>>(x, xbf);

  for (int e0 = 0; e0 < CE; e0 += G) {
    // weight transpose+convert (per-expert gated by eact)
    transcvt<<<dim3(32, 16, G*4), 256, 0, stream>>>(Wq, Wk, Wv, Wo, wT, 1024, 1024, 4, DD, e0, eact);
    transcvt<<<dim3(128, 16, G), 256, 0, stream>>>(W1, W1, W1, W1, w1T, 1024, 4096, 1, DFF, e0, eact);
    transcvt<<<dim3(32, 64, G), 256, 0, stream>>>(W2, W2, W2, W2, w2T, 4096, 1024, 1, DFF, e0, eact);

    // q,k,v = x @ {Wq,Wk,Wv} : z = (ze*3 + mat)
    gemm_nt<128, 128, EPI_BF16, 1><<<dim3(16, 8, G*3), 256, 0, stream>>>(
        xbf, wT, arena, 1024, 1024, 1024, 1024,
        3, 1,
        0, 0, 0,
        4*DD, 0, DD,
        4*BSD, 0, BSD, 0,
        nullptr, 0, gates, e0);

    transpose_v<<<dim3(8, 2, G*CB*CH), 256, 0, stream>>>(arena, arena, gates, e0);

    // fused attention (replaces scores GEMM + softmax + PV)
    attn_fused<<<G*CB*CH, 256, 0, stream>>>(arena, ao, gates, e0);

    // o = ao @ Wo, split-K=2 -> f32 partials in Pb
    gemm_nt<128, 128, EPI_F32, 2><<<dim3(16, 8, G*2), 256, 0, stream>>>(
        ao, wT + 3*DD, PbF, 512, 1024, 1024, 1024,
        1, 1,
        BSD, 0, 0,
        4*DD, 0, 0,
        BSD, 0, 0, (long long)G*BSD,
        nullptr, 0, gates, e0);

    // h = LN(x + o)
    ln1_kernel<<<dim3(2048, G), 256, 0, stream>>>(x, PbF, g1, be1, h, hbf, gates, e0, G);

    // f1 = relu(h @ W1 + b1)  (f1 overlays arena)
    gemm_nt<128, 128, EPI_BRELU, 1><<<dim3(16, 32, G), 256, 0, stream>>>(
        hbf, w1T, arena, 1024, 1024, 1024, 4096,
        1, 1,
        BSD, 0, 0,
        DFF, 0, 0,
        4*BSD, 0, 0, 0,
        b1 + (long long)e0*CFF, CFF, gates, e0);

    // f2 = f1 @ W2 + b2, split-K=4 -> bf16 partials in Pb
    gemm_nt<128, 128, EPI_BIASBF16, 4><<<dim3(16, 8, G*4), 256, 0, stream>>>(
        arena, w2T, PbB, 1024, 4096, 4096, 1024,
        1, 1,
        4*BSD, 0, 0,
        DFF, 0, 0,
        BSD, 0, 0, (long long)G*BSD,
        b2 + (long long)e0*CD, CD, gates, e0);

    // y += gate * LN(h + f2)
    ln2_kernel<<<dim3(2048, G), 256, 0, stream>>>(h, PbB, g2, be2, y, gates, e0, G);
  }

  epsfill<<<8192, 256, 0, stream>>>(y);
}

// Round 4
// 526.451 us; speedup vs baseline: 2.0065x; 1.2089x over previous
//
#include <hip/hip_runtime.h>
#include <hip/hip_bf16.h>

typedef __bf16 bf16;
typedef __attribute__((ext_vector_type(4))) __bf16 bf16x4;
typedef __attribute__((ext_vector_type(8))) __bf16 bf16x8;
typedef __attribute__((ext_vector_type(4))) float floatx4;

constexpr int CB = 8, CS = 256, CD = 1024, CH = 16, CE = 4, CFF = 4096, CHD = 64;
constexpr long long DD  = 1048576;     // D*D
constexpr long long DFF = 4194304;     // D*FF
constexpr long long BSD = 2097152;     // B*S*D
constexpr long long PSD = 4194304;     // 16 pairs * 256 rows * 1024 (compact activation elems)

// ---------- workspace layout (bytes); total ~197.4 MB ----------
constexpr size_t OFF_PART = 0;          // 64*1024 f32 (x column-sum partials)
constexpr size_t OFF_CLEAN= 262144;     // 32 f
constexpr size_t OFF_RAW  = 262272;     // 32 f
constexpr size_t OFF_GATES= 262400;     // 32 f
constexpr size_t OFF_EACT = 262528;     // 4 int
constexpr size_t OFF_PBE  = 262592;     // 16 int: pair -> b | (e<<8)
constexpr size_t OFF_BP   = 262656;     // 16 int: batch -> 2 pair indices
constexpr size_t OFF_XBF  = 263168;     // BSD bf16
constexpr size_t OFF_WT   = OFF_XBF + (size_t)BSD*2;    // 16*DD bf16 (q,k,v,o x 4e)
constexpr size_t OFF_W1T  = OFF_WT  + (size_t)16*DD*2;  // 4*DFF bf16
constexpr size_t OFF_W2T  = OFF_W1T + (size_t)4*DFF*2;  // 4*DFF bf16
constexpr size_t OFF_QKV  = OFF_W2T + (size_t)4*DFF*2;  // 3*PSD bf16 (compact q,k,v)
constexpr size_t OFF_AO   = OFF_QKV + (size_t)3*PSD*2;  // PSD bf16
constexpr size_t OFF_F1   = OFF_QKV;                    // ALIAS: f1 (PSD*4 bf16) over qkv+ao (dead by FF1)
constexpr size_t OFF_PB   = OFF_AO  + (size_t)PSD*2;    // 2*PSD f32 (Wo partials) / 4*PSD bf16 (FF2 partials)
constexpr size_t OFF_VT   = OFF_PB;                     // ALIAS: vT (PSD bf16), dead before Wo writes PbF
constexpr size_t OFF_H    = OFF_PB  + (size_t)2*PSD*4;  // PSD f32
constexpr size_t OFF_HBF  = OFF_H   + (size_t)PSD*4;    // PSD bf16

// ---------- fused convert + column-sum partials ----------
__global__ __launch_bounds__(256)
void cvt_xsum(const float* __restrict__ x, bf16* __restrict__ xbf, float* __restrict__ part) {
  int blk = blockIdx.x;              // 64 = 8 batches x 8 chunks
  int b = blk >> 3, ch = blk & 7;
  int t = threadIdx.x;
  float s0 = 0.f, s1 = 0.f, s2 = 0.f, s3 = 0.f;
  long long base4 = ((long long)(b*CS + ch*32))*CD / 4;
#pragma unroll 4
  for (int r = 0; r < 32; ++r) {
    long long i4 = base4 + (long long)r*(CD/4) + t;
    float4 v = ((const float4*)x)[i4];
    bf16x4 o; o[0] = (bf16)v.x; o[1] = (bf16)v.y; o[2] = (bf16)v.z; o[3] = (bf16)v.w;
    ((bf16x4*)xbf)[i4] = o;
    s0 += v.x; s1 += v.y; s2 += v.z; s3 += v.w;
  }
  float4 sv; sv.x = s0; sv.y = s1; sv.z = s2; sv.w = s3;
  ((float4*)(part + (long long)blk*CD))[t] = sv;
}

__global__ __launch_bounds__(256)
void gate_dots(const float* __restrict__ part, const float* __restrict__ wg,
               const float* __restrict__ wn, float* __restrict__ clean, float* __restrict__ raw) {
  int p = blockIdx.x, b = p >> 2, e = p & 3;
  int t = threadIdx.x;
  float s1 = 0.f, s2 = 0.f;
  for (int d = t; d < CD; d += 256) {
    float xv = 0.f;
#pragma unroll
    for (int c = 0; c < 8; ++c) xv += part[(long long)(b*8 + c)*CD + d];
    s1 += xv * wg[d*CE + e];
    s2 += xv * wn[d*CE + e];
  }
  for (int off = 32; off; off >>= 1) { s1 += __shfl_xor(s1, off); s2 += __shfl_xor(s2, off); }
  __shared__ float r1[4], r2[4];
  int lane = t & 63, w = t >> 6;
  if (lane == 0) { r1[w] = s1; r2[w] = s2; }
  __syncthreads();
  if (t == 0) { clean[p] = r1[0]+r1[1]+r1[2]+r1[3]; raw[p] = r2[0]+r2[1]+r2[2]+r2[3]; }
}

__global__ void gating_kernel(const float* __restrict__ clean, const float* __restrict__ raw,
                              const float* __restrict__ noise, float* __restrict__ gates,
                              int* __restrict__ eact, int* __restrict__ pairBE,
                              int* __restrict__ batchPair, float* __restrict__ loss_out) {
  if (threadIdx.x != 0) return;
  float imp[CE] = {0,0,0,0}, load[CE] = {0,0,0,0};
  int act[CE] = {0,0,0,0};
  for (int b = 0; b < CB; ++b) {
    float cl[CE], sd[CE], ny[CE];
    for (int e = 0; e < CE; ++e) {
      cl[e] = clean[b*CE + e];
      float rw = raw[b*CE + e];
      float sp = fmaxf(rw, 0.f) + log1pf(expf(-fabsf(rw)));   // stable softplus
      sd[e] = sp + 0.01f;
      ny[e] = cl[e] + noise[b*CE + e]*sd[e];
    }
    int idx[CE] = {0,1,2,3};
    for (int a = 0; a < 3; ++a) {            // selection sort desc, stable
      int best = a;
      for (int c = a + 1; c < 4; ++c) if (ny[idx[c]] > ny[idx[best]]) best = c;
      int tt = idx[a]; idx[a] = idx[best]; idx[best] = tt;
    }
    float l0 = ny[idx[0]], l1 = ny[idx[1]], l2 = ny[idx[2]];
    float e1 = expf(l1 - l0);
    float g0 = 1.f/(1.f + e1), g1v = e1/(1.f + e1);
    for (int e = 0; e < CE; ++e) gates[b*CE + e] = 0.f;
    gates[b*CE + idx[0]] = g0; gates[b*CE + idx[1]] = g1v;
    imp[idx[0]] += g0; imp[idx[1]] += g1v;
    act[idx[0]] = 1; act[idx[1]] = 1;
    for (int e = 0; e < CE; ++e) {
      bool is_in = ny[e] > l2;
      float thr = is_in ? l2 : l1;
      float zz = (cl[e] - thr) / sd[e];
      load[e] += 0.5f * erfcf(-zz * 0.70710678118654752440f);
    }
  }
  // compact pair list (sorted by expert, then batch) — always exactly 16 pairs
  int pe2p[CB][CE];
  int pc = 0;
  for (int e = 0; e < CE; ++e)
    for (int b = 0; b < CB; ++b)
      if (gates[b*CE + e] != 0.f) { pairBE[pc] = b | (e << 8); pe2p[b][e] = pc; ++pc; }
  for (int b = 0; b < CB; ++b) {
    int s = 0;
    for (int e = 0; e < CE; ++e)
      if (gates[b*CE + e] != 0.f) batchPair[2*b + (s++)] = pe2p[b][e];
  }
  float m1 = 0.f, m2 = 0.f;
  for (int e = 0; e < CE; ++e) { m1 += imp[e]; m2 += load[e]; }
  m1 *= 0.25f; m2 *= 0.25f;
  float v1 = 0.f, v2 = 0.f;
  for (int e = 0; e < CE; ++e) { float d1 = imp[e]-m1, d2 = load[e]-m2; v1 += d1*d1; v2 += d2*d2; }
  v1 *= (1.f/3.f); v2 *= (1.f/3.f);
  loss_out[0] = 0.01f * (v1/(m1*m1 + 1e-10f) + v2/(m2*m2 + 1e-10f));
  for (int e = 0; e < CE; ++e) eact[e] = act[e];
}

// ---------- unified weight transpose+convert (one dispatch for all 24 matrices) ----------
__global__ __launch_bounds__(256)
void transcvt_all(const float* __restrict__ Wq, const float* __restrict__ Wk,
                  const float* __restrict__ Wv, const float* __restrict__ Wo,
                  const float* __restrict__ W1, const float* __restrict__ W2,
                  bf16* __restrict__ wT, bf16* __restrict__ w1T, bf16* __restrict__ w2T,
                  const int* __restrict__ eact) {
  int z = blockIdx.x;
  const float* src; bf16* d; int rows, cols, tx, ty, e;
  if (z < 8192) {                     // Wq/Wk/Wv/Wo: 16 mats of 1024x1024, 512 tiles each
    int m = z >> 9, t = z & 511; e = m >> 2; int which = m & 3;
    src = ((which == 0) ? Wq : (which == 1) ? Wk : (which == 2) ? Wv : Wo) + (long long)e*DD;
    d = wT + (long long)m*DD; rows = 1024; cols = 1024;
    tx = t & 31; ty = t >> 5;
  } else if (z < 16384) {             // W1: 4 mats of 1024x4096, 2048 tiles each
    int z2 = z - 8192; e = z2 >> 11; int t = z2 & 2047;
    src = W1 + (long long)e*DFF; d = w1T + (long long)e*DFF;
    rows = 1024; cols = 4096; tx = t & 127; ty = t >> 7;
  } else {                            // W2: 4 mats of 4096x1024, 2048 tiles each
    int z3 = z - 16384; e = z3 >> 11; int t = z3 & 2047;
    src = W2 + (long long)e*DFF; d = w2T + (long long)e*DFF;
    rows = 4096; cols = 1024; tx = t & 31; ty = t >> 5;
  }
  if (eact[e] == 0) return;
  __shared__ float tile[64][33];
  int c0 = tx*32, r0 = ty*64;
  int t = threadIdx.x;
#pragma unroll
  for (int i = 0; i < 8; ++i) {
    int id = i*256 + t; int r = id >> 5, c = id & 31;
    tile[r][c] = src[(long long)(r0 + r)*cols + c0 + c];
  }
  __syncthreads();
  unsigned* dw = (unsigned*)d;
#pragma unroll
  for (int i = 0; i < 4; ++i) {
    int id = i*256 + t; int dr = id >> 5, c = id & 31;
    union { bf16 h[2]; unsigned u; } pk;
    pk.h[0] = (bf16)tile[2*c][dr]; pk.h[1] = (bf16)tile[2*c + 1][dr];
    dw[((long long)(c0 + dr)*rows + r0)/2 + c] = pk.u;
  }
}

// v (compact slot 2, [pair][s][(h,hd)]) -> vT ([pair][h][hd][s])
__global__ __launch_bounds__(256)
void transpose_v(const bf16* __restrict__ qkvC, bf16* __restrict__ vTb) {
  int z = blockIdx.z; int p = z >> 4, h = z & 15;
  const bf16* v = qkvC + 2*PSD + (long long)(p*CS)*CD + h*CHD;
  bf16* vt = vTb + (long long)(p*CH + h)*CHD*CS;
  __shared__ bf16 tile[32][33];
  int s0 = blockIdx.x*32, d0 = blockIdx.y*32;
  int tx = threadIdx.x % 32, ty = threadIdx.x / 32;
#pragma unroll
  for (int i = 0; i < 4; ++i)
    tile[ty + 8*i][tx] = v[(long long)(s0 + ty + 8*i)*CD + d0 + tx];
  __syncthreads();
#pragma unroll
  for (int i = 0; i < 4; ++i)
    vt[(long long)(d0 + ty + 8*i)*CS + s0 + tx] = tile[tx][ty + 8*i];
}

// ---------- async staging (global_load_lds width=16, XOR-swizzled on the global side) ----------
__device__ __forceinline__ void cp16(const bf16* g, bf16* l) {
  __builtin_amdgcn_global_load_lds((const __attribute__((address_space(1))) void*)g,
                                   (__attribute__((address_space(3))) void*)l, 16, 0, 0);
}

template<int R, int W>
__device__ __forceinline__ void stage(const bf16* __restrict__ src, int ld, bf16* dst) {
  constexpr int W8 = W/8;
  int t = threadIdx.x;
  int l = t & 63, wid = t >> 6;
#pragma unroll
  for (int i = 0; i < (R*W8)/256; ++i) {
    int idb = i*256 + wid*64;         // wave-uniform LDS base (chunk units)
    int id = idb + l;
    int row = id / W8, sl = id % W8;
    int gc = sl ^ (row & 7);          // XOR self-inverse
    cp16(src + (long long)row*ld + gc*8, dst + (long long)idb*8);
  }
}

// ---------- fused flash attention: block per (pair, head) ----------
__global__ __launch_bounds__(256)
void attn_fused(const bf16* __restrict__ qkvC, const bf16* __restrict__ vTb,
                bf16* __restrict__ aoC) {
  int h = blockIdx.x, p = blockIdx.y;
  const bf16* qp = qkvC + (long long)(p*CS)*CD + h*CHD;
  const bf16* kp = qp + PSD;
  const bf16* vt = vTb + (long long)(p*CH + h)*CHD*CS;
  bf16* aop = aoC + (long long)(p*CS)*CD + h*CHD;

  __shared__ bf16 Ps[64*264];
  __shared__ float smaxL[64*4], ssumL[64*4], Lrow[64];

  int t = threadIdx.x, w = t >> 6, lane = t & 63, lr = lane & 15, quad = lane >> 4;

  for (int qt = 0; qt < 4; ++qt) {
    floatx4 accs[4][4] = {};
#pragma unroll
    for (int kk = 0; kk < 2; ++kk) {
      int c = kk*4 + quad;
      bf16x8 af[4], bfr[4];
#pragma unroll
      for (int i = 0; i < 4; ++i) {
        af[i]  = *(const bf16x8*)(qp + (long long)(qt*64 + i*16 + lr)*CD + c*8);
        bfr[i] = *(const bf16x8*)(kp + (long long)(w*64  + i*16 + lr)*CD + c*8);
      }
#pragma unroll
      for (int i = 0; i < 4; ++i)
#pragma unroll
        for (int j = 0; j < 4; ++j)
          accs[i][j] = __builtin_amdgcn_mfma_f32_16x16x32_bf16(af[i], bfr[j], accs[i][j], 0, 0, 0);
    }
    float rmax[4][4];
#pragma unroll
    for (int i = 0; i < 4; ++i)
#pragma unroll
      for (int r = 0; r < 4; ++r) {
        int qrow = qt*64 + i*16 + quad*4 + r;
        float m = -3.0e38f;
#pragma unroll
        for (int j = 0; j < 4; ++j) {
          int kcol = w*64 + j*16 + lr;
          float s = accs[i][j][r]*0.125f;
          s = (kcol <= qrow) ? s : -3.0e38f;
          accs[i][j][r] = s;
          m = fmaxf(m, s);
        }
        rmax[i][r] = m;
      }
#pragma unroll
    for (int off = 1; off <= 8; off <<= 1)
#pragma unroll
      for (int i = 0; i < 4; ++i)
#pragma unroll
        for (int r = 0; r < 4; ++r) rmax[i][r] = fmaxf(rmax[i][r], __shfl_xor(rmax[i][r], off));
    if (lr == 0)
#pragma unroll
      for (int i = 0; i < 4; ++i)
#pragma unroll
        for (int r = 0; r < 4; ++r) smaxL[(i*16 + quad*4 + r)*4 + w] = rmax[i][r];
    __syncthreads();
    float rsum[4][4];
#pragma unroll
    for (int i = 0; i < 4; ++i)
#pragma unroll
      for (int r = 0; r < 4; ++r) {
        floatx4 mv = *(const floatx4*)&smaxL[(i*16 + quad*4 + r)*4];
        float M = fmaxf(fmaxf(mv[0], mv[1]), fmaxf(mv[2], mv[3]));
        float srow = 0.f;
#pragma unroll
        for (int j = 0; j < 4; ++j) {
          float pp = __expf(accs[i][j][r] - M);
          accs[i][j][r] = pp;
          srow += pp;
        }
        rsum[i][r] = srow;
      }
#pragma unroll
    for (int off = 1; off <= 8; off <<= 1)
#pragma unroll
      for (int i = 0; i < 4; ++i)
#pragma unroll
        for (int r = 0; r < 4; ++r) rsum[i][r] += __shfl_xor(rsum[i][r], off);
    if (lr == 0)
#pragma unroll
      for (int i = 0; i < 4; ++i)
#pragma unroll
        for (int r = 0; r < 4; ++r) ssumL[(i*16 + quad*4 + r)*4 + w] = rsum[i][r];
    __syncthreads();
    if (w == 0 && lr == 0) {
#pragma unroll
      for (int i = 0; i < 4; ++i)
#pragma unroll
        for (int r = 0; r < 4; ++r) {
          int m = i*16 + quad*4 + r;
          floatx4 sv = *(const floatx4*)&ssumL[m*4];
          Lrow[m] = sv[0] + sv[1] + sv[2] + sv[3];
        }
    }
#pragma unroll
    for (int i = 0; i < 4; ++i)
#pragma unroll
      for (int j = 0; j < 4; ++j)
#pragma unroll
        for (int r = 0; r < 4; ++r)
          Ps[(i*16 + quad*4 + r)*264 + w*64 + j*16 + lr] = (bf16)accs[i][j][r];
    __syncthreads();
    floatx4 acco[4] = {};
#pragma unroll
    for (int ks = 0; ks < 8; ++ks) {
      int c = ks*4 + quad;
      bf16x8 ap = *(const bf16x8*)(Ps + (w*16 + lr)*264 + c*8);
#pragma unroll
      for (int j = 0; j < 4; ++j) {
        bf16x8 bv = *(const bf16x8*)(vt + (long long)(j*16 + lr)*CS + c*8);
        acco[j] = __builtin_amdgcn_mfma_f32_16x16x32_bf16(ap, bv, acco[j], 0, 0, 0);
      }
    }
#pragma unroll
    for (int r = 0; r < 4; ++r) {
      int orow = w*16 + quad*4 + r;
      float inv = 1.f / Lrow[orow];
#pragma unroll
      for (int j = 0; j < 4; ++j)
        aop[(long long)(qt*64 + orow)*CD + j*16 + lr] = (bf16)(acco[j][r]*inv);
    }
    __syncthreads();
  }
}

// ---------- layernorms ----------
// h = LN(x + WoPartial0 + WoPartial1); writes f32 + bf16 (compact rows)
__global__ __launch_bounds__(256)
void ln1_kernel(const float* __restrict__ x, const float* __restrict__ PbF,
                const float* __restrict__ gamma, const float* __restrict__ beta,
                float* __restrict__ h, bf16* __restrict__ hbf, const int* __restrict__ pairBE) {
  int row = blockIdx.x;                     // 0..4095 compact
  int pbe = pairBE[row >> 8]; int pb = pbe & 255, pe = pbe >> 8;
  int t = threadIdx.x;
  const float* pa = x + ((long long)pb*CS + (row & 255))*CD;
  const float* p0 = PbF + (long long)row*CD;
  const float* p1 = PbF + PSD + (long long)row*CD;
  const float* gm = gamma + (long long)pe*CD;
  const float* bt = beta  + (long long)pe*CD;
  float v[4]; float s = 0.f, s2 = 0.f;
#pragma unroll
  for (int i = 0; i < 4; ++i) {
    int d = t + 256*i;
    float xv = pa[d] + p0[d] + p1[d];
    v[i] = xv; s += xv; s2 += xv*xv;
  }
  int lane = t & 63, wave = t >> 6;
  for (int off = 32; off; off >>= 1) { s += __shfl_xor(s, off); s2 += __shfl_xor(s2, off); }
  __shared__ float red[8];
  if (lane == 0) { red[wave*2] = s; red[wave*2 + 1] = s2; }
  __syncthreads();
  s  = red[0] + red[2] + red[4] + red[6];
  s2 = red[1] + red[3] + red[5] + red[7];
  float mean = s * (1.f/CD);
  float var  = s2 * (1.f/CD) - mean*mean;
  float rstd = rsqrtf(var + 1e-5f);
#pragma unroll
  for (int i = 0; i < 4; ++i) {
    int d = t + 256*i;
    float val = (v[i] - mean)*rstd*gm[d] + bt[d];
    h  [(long long)row*CD + d] = val;
    hbf[(long long)row*CD + d] = (bf16)val;
  }
}

// y = epsfill( gate0*LN(h[p0]+f2[p0]) + gate1*LN(h[p1]+f2[p1]) )  — one block per (b,s) row
__global__ __launch_bounds__(256)
void ln2y_kernel(const float* __restrict__ h, const bf16* __restrict__ PbB,
                 const float* __restrict__ gamma, const float* __restrict__ beta,
                 float* __restrict__ y, const float* __restrict__ gates,
                 const int* __restrict__ pairBE, const int* __restrict__ batchPair) {
  int row = blockIdx.x;                     // 0..2047 = b*256 + s
  int b = row >> 8, sIdx = row & 255;
  int p0 = batchPair[2*b], p1 = batchPair[2*b + 1];
  int e0 = pairBE[p0] >> 8, e1 = pairBE[p1] >> 8;
  float gv0 = gates[b*CE + e0], gv1 = gates[b*CE + e1];
  long long r0 = (long long)p0*CS + sIdx, r1 = (long long)p1*CS + sIdx;
  int t = threadIdx.x;
  float v0[4], v1[4];
  float sA = 0.f, sA2 = 0.f, sB = 0.f, sB2 = 0.f;
#pragma unroll
  for (int i = 0; i < 4; ++i) {
    int d = t + 256*i;
    float a = h[r0*CD + d];
    float c = h[r1*CD + d];
#pragma unroll
    for (int k = 0; k < 4; ++k) {
      a += (float)PbB[(long long)k*PSD + r0*CD + d];
      c += (float)PbB[(long long)k*PSD + r1*CD + d];
    }
    v0[i] = a; sA += a; sA2 += a*a;
    v1[i] = c; sB += c; sB2 += c*c;
  }
  int lane = t & 63, wave = t >> 6;
  for (int off = 32; off; off >>= 1) {
    sA += __shfl_xor(sA, off); sA2 += __shfl_xor(sA2, off);
    sB += __shfl_xor(sB, off); sB2 += __shfl_xor(sB2, off);
  }
  __shared__ float red[16];
  if (lane == 0) { red[wave*4] = sA; red[wave*4+1] = sA2; red[wave*4+2] = sB; red[wave*4+3] = sB2; }
  __syncthreads();
  sA  = red[0] + red[4] + red[8]  + red[12];
  sA2 = red[1] + red[5] + red[9]  + red[13];
  sB  = red[2] + red[6] + red[10] + red[14];
  sB2 = red[3] + red[7] + red[11] + red[15];
  float mA = sA*(1.f/CD), mB = sB*(1.f/CD);
  float rsA = rsqrtf(sA2*(1.f/CD) - mA*mA + 1e-5f);
  float rsB = rsqrtf(sB2*(1.f/CD) - mB*mB + 1e-5f);
  const float* gm0 = gamma + (long long)e0*CD; const float* bt0 = beta + (long long)e0*CD;
  const float* gm1 = gamma + (long long)e1*CD; const float* bt1 = beta + (long long)e1*CD;
#pragma unroll
  for (int i = 0; i < 4; ++i) {
    int d = t + 256*i;
    float o = gv0*((v0[i] - mA)*rsA*gm0[d] + bt0[d]) + gv1*((v1[i] - mB)*rsB*gm1[d] + bt1[d]);
    y[(long long)row*CD + d] = (o == 0.f) ? 2.2204460492503131e-16f : o;
  }
}

// ---------- MFMA GEMM on compact pairs:  C[M,N] = A[M,K] * Bt[N,K]^T ----------
enum { EPI_BF16 = 0, EPI_F32 = 1, EPI_BRELU = 2, EPI_BIASBF16 = 3 };

template<int EPI, int KS, bool A_BATCH>
__global__ __launch_bounds__(256)
void gemm_nt(const bf16* __restrict__ A, const bf16* __restrict__ Bt, void* __restrict__ Cv,
             int K /*per split*/, int lda, int ldb, int ldc,
             long long oBe, long long oBmat, long long oCmat, long long oCk,
             const float* __restrict__ bias, long long biasStride,
             const int* __restrict__ pairBE) {
  constexpr int BM = 128, BN = 128;
  int z = blockIdx.z;
  int zk = z % KS, mat = z / KS;
  int m0 = blockIdx.x * BM, n0 = blockIdx.y * BN;
  int pbe = pairBE[m0 >> 8]; int pb = pbe & 255, pe = pbe >> 8;
  const bf16* Ab = A + (A_BATCH ? ((long long)pb*CS + (m0 & 255))*lda : (long long)m0*lda)
                     + (long long)zk*K;
  const bf16* Bb = Bt + (long long)pe*oBe + (long long)mat*oBmat + (long long)zk*K
                      + (long long)n0*ldb;
  long long coff = (long long)mat*oCmat + (long long)zk*oCk;

  __shared__ bf16 As[BM*64];
  __shared__ bf16 Bs[BN*64];

  int wave = threadIdx.x >> 6;
  int lane = threadIdx.x & 63;
  int wm = wave >> 1, wn = wave & 1;
  int lr = lane & 15;
  int quad = lane >> 4;

  floatx4 acc[4][4] = {};

  for (int kt = 0; kt < K; kt += 64) {
    stage<BM, 64>(Ab + kt, lda, As);
    stage<BN, 64>(Bb + kt, ldb, Bs);
    __syncthreads();
#pragma unroll
    for (int kk = 0; kk < 2; ++kk) {
      bf16x8 af[4], bfr[4];
#pragma unroll
      for (int i = 0; i < 4; ++i) {
        int c = kk*4 + quad;
        int m = wm*64 + i*16 + lr;
        af[i]  = *(const bf16x8*)(As + m*64 + ((c ^ (m & 7))*8));
        int n = wn*64 + i*16 + lr;
        bfr[i] = *(const bf16x8*)(Bs + n*64 + ((c ^ (n & 7))*8));
      }
#pragma unroll
      for (int i = 0; i < 4; ++i)
#pragma unroll
        for (int j = 0; j < 4; ++j)
          acc[i][j] = __builtin_amdgcn_mfma_f32_16x16x32_bf16(af[i], bfr[j], acc[i][j], 0, 0, 0);
    }
    __syncthreads();
  }

#pragma unroll
  for (int j = 0; j < 4; ++j) {
    int col = n0 + wn*64 + j*16 + lr;
    float bv = 0.f;
    if constexpr (EPI == EPI_BRELU || EPI == EPI_BIASBF16)
      if (zk == 0) bv = bias[(long long)pe*biasStride + col];
#pragma unroll
    for (int i = 0; i < 4; ++i) {
#pragma unroll
      for (int r = 0; r < 4; ++r) {
        int row = m0 + wm*64 + i*16 + quad*4 + r;
        float v = acc[i][j][r] + bv;
        long long idx = coff + (long long)row*ldc + col;
        if constexpr (EPI == EPI_BF16)          ((bf16*)Cv)[idx] = (bf16)v;
        else if constexpr (EPI == EPI_F32)      ((float*)Cv)[idx] = v;
        else if constexpr (EPI == EPI_BRELU)    ((bf16*)Cv)[idx] = (bf16)fmaxf(v, 0.f);
        else                                    ((bf16*)Cv)[idx] = (bf16)v;
      }
    }
  }
}

// ---------- launch ----------
extern "C" void kernel_launch(void* const* d_in, const int* in_sizes, int n_in,
                              void* d_out, int out_size, void* d_ws, size_t ws_size,
                              hipStream_t stream) {
  const float* x       = (const float*)d_in[0];
  const float* noise   = (const float*)d_in[2];
  const float* w_gate  = (const float*)d_in[3];
  const float* w_noise = (const float*)d_in[4];
  const float* Wq      = (const float*)d_in[5];
  const float* Wk      = (const float*)d_in[6];
  const float* Wv      = (const float*)d_in[7];
  const float* Wo      = (const float*)d_in[8];
  const float* W1      = (const float*)d_in[9];
  const float* b1      = (const float*)d_in[10];
  const float* W2      = (const float*)d_in[11];
  const float* b2      = (const float*)d_in[12];
  const float* g1      = (const float*)d_in[13];
  const float* be1     = (const float*)d_in[14];
  const float* g2      = (const float*)d_in[15];
  const float* be2     = (const float*)d_in[16];

  char* ws = (char*)d_ws;
  float* y    = (float*)d_out;
  float* loss = y + (size_t)BSD;

  float* part  = (float*)(ws + OFF_PART);
  float* clean = (float*)(ws + OFF_CLEAN);
  float* raw   = (float*)(ws + OFF_RAW);
  float* gates = (float*)(ws + OFF_GATES);
  int*   eact  = (int*)  (ws + OFF_EACT);
  int*   pairBE= (int*)  (ws + OFF_PBE);
  int*   batchPair = (int*)(ws + OFF_BP);
  bf16*  xbf   = (bf16*) (ws + OFF_XBF);
  bf16*  wT    = (bf16*) (ws + OFF_WT);
  bf16*  w1T   = (bf16*) (ws + OFF_W1T);
  bf16*  w2T   = (bf16*) (ws + OFF_W2T);
  bf16*  qkvC  = (bf16*) (ws + OFF_QKV);
  bf16*  aoC   = (bf16*) (ws + OFF_AO);
  bf16*  f1    = (bf16*) (ws + OFF_F1);
  bf16*  vTb   = (bf16*) (ws + OFF_VT);
  float* PbF   = (float*)(ws + OFF_PB);
  bf16*  PbB   = (bf16*) (ws + OFF_PB);
  float* h     = (float*)(ws + OFF_H);
  bf16*  hbf   = (bf16*) (ws + OFF_HBF);

  cvt_xsum<<<64, 256, 0, stream>>>(x, xbf, part);
  gate_dots<<<32, 256, 0, stream>>>(part, w_gate, w_noise, clean, raw);
  gating_kernel<<<1, 64, 0, stream>>>(clean, raw, noise, gates, eact, pairBE, batchPair, loss);
  transcvt_all<<<24576, 256, 0, stream>>>(Wq, Wk, Wv, Wo, W1, W2, wT, w1T, w2T, eact);

  // q,k,v = x @ {Wq,Wk,Wv}  (compact M = 16 pairs x 256)
  gemm_nt<EPI_BF16, 1, true><<<dim3(32, 8, 3), 256, 0, stream>>>(
      xbf, wT, qkvC, 1024, 1024, 1024, 1024,
      4*DD, DD, PSD, 0, nullptr, 0, pairBE);

  transpose_v<<<dim3(8, 2, 256), 256, 0, stream>>>(qkvC, vTb);

  attn_fused<<<dim3(CH, 16), 256, 0, stream>>>(qkvC, vTb, aoC);

  // o = ao @ Wo, split-K=2 -> f32 partials
  gemm_nt<EPI_F32, 2, false><<<dim3(32, 8, 2), 256, 0, stream>>>(
      aoC, wT + 3*DD, PbF, 512, 1024, 1024, 1024,
      4*DD, 0, 0, PSD, nullptr, 0, pairBE);

  // h = LN(x + o)
  ln1_kernel<<<4096, 256, 0, stream>>>(x, PbF, g1, be1, h, hbf, pairBE);

  // f1 = relu(h @ W1 + b1)   (f1 overlays qkv+ao)
  gemm_nt<EPI_BRELU, 1, false><<<dim3(32, 32, 1), 256, 0, stream>>>(
      hbf, w1T, f1, 1024, 1024, 1024, 4096,
      DFF, 0, 0, 0, b1, CFF, pairBE);

  // f2 = f1 @ W2 + b2, split-K=4 -> bf16 partials
  gemm_nt<EPI_BIASBF16, 4, false><<<dim3(32, 8, 4), 256, 0, stream>>>(
      f1, w2T, PbB, 1024, 4096, 4096, 1024,
      DFF, 0, 0, PSD, b2, CD, pairBE);

  // y = epsfill( sum of gate * LN(h + f2) over the batch's 2 active pairs )
  ln2y_kernel<<<2048, 256, 0, stream>>>(h, PbB, g2, be2, y, gates, pairBE, batchPair);
}

// Round 5
// 518.804 us; speedup vs baseline: 2.0361x; 1.0147x over previous
//
#include <hip/hip_runtime.h>
#include <hip/hip_bf16.h>

typedef __bf16 bf16;
typedef __attribute__((ext_vector_type(4))) __bf16 bf16x4;
typedef __attribute__((ext_vector_type(8))) __bf16 bf16x8;
typedef __attribute__((ext_vector_type(4))) float floatx4;

constexpr int CB = 8, CS = 256, CD = 1024, CH = 16, CE = 4, CFF = 4096, CHD = 64;
constexpr long long DD  = 1048576;     // D*D
constexpr long long DFF = 4194304;     // D*FF
constexpr long long BSD = 2097152;     // B*S*D
constexpr long long PSD = 4194304;     // 16 pairs * 256 rows * 1024 (compact activation elems)

// ---------- workspace layout (bytes) ----------
constexpr size_t OFF_PART = 0;          // 64*1024 f32 (x column-sum partials)
constexpr size_t OFF_CLEAN= 262144;     // 32 f
constexpr size_t OFF_RAW  = 262272;     // 32 f
constexpr size_t OFF_GATES= 262400;     // 32 f
constexpr size_t OFF_EACT = 262528;     // 4 int
constexpr size_t OFF_PBE  = 262592;     // 16 int: pair -> b | (e<<8)
constexpr size_t OFF_BP   = 262656;     // 16 int: batch -> 2 pair indices
constexpr size_t OFF_XBF  = 263168;     // BSD bf16
constexpr size_t OFF_WT   = OFF_XBF + (size_t)BSD*2;    // 16*DD bf16 (q,k,v,o x 4e)
constexpr size_t OFF_W1T  = OFF_WT  + (size_t)16*DD*2;  // 4*DFF bf16
constexpr size_t OFF_W2T  = OFF_W1T + (size_t)4*DFF*2;  // 4*DFF bf16
constexpr size_t OFF_QKV  = OFF_W2T + (size_t)4*DFF*2;  // 3*PSD bf16 (compact q,k,v)
constexpr size_t OFF_AO   = OFF_QKV + (size_t)3*PSD*2;  // PSD bf16
constexpr size_t OFF_F1   = OFF_QKV;                    // ALIAS: f1 (PSD*4 bf16) over qkv+ao (dead by FF1)
constexpr size_t OFF_PB   = OFF_AO  + (size_t)PSD*2;    // 2*PSD f32 (Wo partials) / 4*PSD bf16 (FF2 partials)
constexpr size_t OFF_VT   = OFF_PB;                     // ALIAS: vT (PSD bf16), dead before Wo writes PbF
constexpr size_t OFF_H    = OFF_PB  + (size_t)2*PSD*4;  // PSD f32
constexpr size_t OFF_HBF  = OFF_H   + (size_t)PSD*4;    // PSD bf16

// ---------- fused convert + column-sum partials ----------
__global__ __launch_bounds__(256)
void cvt_xsum(const float* __restrict__ x, bf16* __restrict__ xbf, float* __restrict__ part) {
  int blk = blockIdx.x;              // 64 = 8 batches x 8 chunks
  int b = blk >> 3, ch = blk & 7;
  int t = threadIdx.x;
  float s0 = 0.f, s1 = 0.f, s2 = 0.f, s3 = 0.f;
  long long base4 = ((long long)(b*CS + ch*32))*CD / 4;
#pragma unroll 4
  for (int r = 0; r < 32; ++r) {
    long long i4 = base4 + (long long)r*(CD/4) + t;
    float4 v = ((const float4*)x)[i4];
    bf16x4 o; o[0] = (bf16)v.x; o[1] = (bf16)v.y; o[2] = (bf16)v.z; o[3] = (bf16)v.w;
    ((bf16x4*)xbf)[i4] = o;
    s0 += v.x; s1 += v.y; s2 += v.z; s3 += v.w;
  }
  float4 sv; sv.x = s0; sv.y = s1; sv.z = s2; sv.w = s3;
  ((float4*)(part + (long long)blk*CD))[t] = sv;
}

__global__ __launch_bounds__(256)
void gate_dots(const float* __restrict__ part, const float* __restrict__ wg,
               const float* __restrict__ wn, float* __restrict__ clean, float* __restrict__ raw) {
  int p = blockIdx.x, b = p >> 2, e = p & 3;
  int t = threadIdx.x;
  float s1 = 0.f, s2 = 0.f;
  for (int d = t; d < CD; d += 256) {
    float xv = 0.f;
#pragma unroll
    for (int c = 0; c < 8; ++c) xv += part[(long long)(b*8 + c)*CD + d];
    s1 += xv * wg[d*CE + e];
    s2 += xv * wn[d*CE + e];
  }
  for (int off = 32; off; off >>= 1) { s1 += __shfl_xor(s1, off); s2 += __shfl_xor(s2, off); }
  __shared__ float r1[4], r2[4];
  int lane = t & 63, w = t >> 6;
  if (lane == 0) { r1[w] = s1; r2[w] = s2; }
  __syncthreads();
  if (t == 0) { clean[p] = r1[0]+r1[1]+r1[2]+r1[3]; raw[p] = r2[0]+r2[1]+r2[2]+r2[3]; }
}

__global__ void gating_kernel(const float* __restrict__ clean, const float* __restrict__ raw,
                              const float* __restrict__ noise, float* __restrict__ gates,
                              int* __restrict__ eact, int* __restrict__ pairBE,
                              int* __restrict__ batchPair, float* __restrict__ loss_out) {
  if (threadIdx.x != 0) return;
  float imp[CE] = {0,0,0,0}, load[CE] = {0,0,0,0};
  int act[CE] = {0,0,0,0};
  for (int b = 0; b < CB; ++b) {
    float cl[CE], sd[CE], ny[CE];
    for (int e = 0; e < CE; ++e) {
      cl[e] = clean[b*CE + e];
      float rw = raw[b*CE + e];
      float sp = fmaxf(rw, 0.f) + log1pf(expf(-fabsf(rw)));   // stable softplus
      sd[e] = sp + 0.01f;
      ny[e] = cl[e] + noise[b*CE + e]*sd[e];
    }
    int idx[CE] = {0,1,2,3};
    for (int a = 0; a < 3; ++a) {            // selection sort desc, stable
      int best = a;
      for (int c = a + 1; c < 4; ++c) if (ny[idx[c]] > ny[idx[best]]) best = c;
      int tt = idx[a]; idx[a] = idx[best]; idx[best] = tt;
    }
    float l0 = ny[idx[0]], l1 = ny[idx[1]], l2 = ny[idx[2]];
    float e1 = expf(l1 - l0);
    float g0 = 1.f/(1.f + e1), g1v = e1/(1.f + e1);
    for (int e = 0; e < CE; ++e) gates[b*CE + e] = 0.f;
    gates[b*CE + idx[0]] = g0; gates[b*CE + idx[1]] = g1v;
    imp[idx[0]] += g0; imp[idx[1]] += g1v;
    act[idx[0]] = 1; act[idx[1]] = 1;
    for (int e = 0; e < CE; ++e) {
      bool is_in = ny[e] > l2;
      float thr = is_in ? l2 : l1;
      float zz = (cl[e] - thr) / sd[e];
      load[e] += 0.5f * erfcf(-zz * 0.70710678118654752440f);
    }
  }
  // compact pair list (sorted by expert, then batch) — always exactly 16 pairs
  int pe2p[CB][CE];
  int pc = 0;
  for (int e = 0; e < CE; ++e)
    for (int b = 0; b < CB; ++b)
      if (gates[b*CE + e] != 0.f) { pairBE[pc] = b | (e << 8); pe2p[b][e] = pc; ++pc; }
  for (int b = 0; b < CB; ++b) {
    int s = 0;
    for (int e = 0; e < CE; ++e)
      if (gates[b*CE + e] != 0.f) batchPair[2*b + (s++)] = pe2p[b][e];
  }
  float m1 = 0.f, m2 = 0.f;
  for (int e = 0; e < CE; ++e) { m1 += imp[e]; m2 += load[e]; }
  m1 *= 0.25f; m2 *= 0.25f;
  float v1 = 0.f, v2 = 0.f;
  for (int e = 0; e < CE; ++e) { float d1 = imp[e]-m1, d2 = load[e]-m2; v1 += d1*d1; v2 += d2*d2; }
  v1 *= (1.f/3.f); v2 *= (1.f/3.f);
  loss_out[0] = 0.01f * (v1/(m1*m1 + 1e-10f) + v2/(m2*m2 + 1e-10f));
  for (int e = 0; e < CE; ++e) eact[e] = act[e];
}

// ---------- unified weight transpose+convert v2 ----------
// 64(k) x 64(n) tiles; float4 global reads, LDS [64][65] (<=2-way banks both phases),
// bf16x8 coalesced stores (8-lane 128B segments). 12288 blocks.
__global__ __launch_bounds__(256)
void transcvt_all(const float* __restrict__ Wq, const float* __restrict__ Wk,
                  const float* __restrict__ Wv, const float* __restrict__ Wo,
                  const float* __restrict__ W1, const float* __restrict__ W2,
                  bf16* __restrict__ wT, bf16* __restrict__ w1T, bf16* __restrict__ w2T,
                  const int* __restrict__ eact) {
  int z = blockIdx.x;
  const float* src; bf16* d; int rows, cols, tk, tn, e;
  if (z < 4096) {                     // Wq/Wk/Wv/Wo: 16 mats of [1024][1024], 256 tiles each
    int m = z >> 8, tt = z & 255; e = m >> 2; int which = m & 3;
    src = ((which == 0) ? Wq : (which == 1) ? Wk : (which == 2) ? Wv : Wo) + (long long)e*DD;
    d = wT + (long long)m*DD; rows = 1024; cols = 1024;
    tk = tt >> 4; tn = tt & 15;
  } else if (z < 8192) {              // W1: 4 mats of [1024][4096], 1024 tiles each
    int z2 = z - 4096; e = z2 >> 10; int tt = z2 & 1023;
    src = W1 + (long long)e*DFF; d = w1T + (long long)e*DFF;
    rows = 1024; cols = 4096; tk = tt >> 6; tn = tt & 63;
  } else {                            // W2: 4 mats of [4096][1024], 1024 tiles each
    int z3 = z - 8192; e = z3 >> 10; int tt = z3 & 1023;
    src = W2 + (long long)e*DFF; d = w2T + (long long)e*DFF;
    rows = 4096; cols = 1024; tk = tt >> 4; tn = tt & 15;
  }
  if (eact[e] == 0) return;
  __shared__ float tile[64][65];
  int t = threadIdx.x;
  int k0 = tk*64, n0 = tn*64;
  // phase 1: 4 passes of 16 rows x 16 float4
#pragma unroll
  for (int i = 0; i < 4; ++i) {
    int id = i*256 + t; int r = id >> 4, c4 = id & 15;
    float4 v = *(const float4*)&src[(long long)(k0 + r)*cols + n0 + c4*4];
    tile[r][c4*4 + 0] = v.x; tile[r][c4*4 + 1] = v.y;
    tile[r][c4*4 + 2] = v.z; tile[r][c4*4 + 3] = v.w;
  }
  __syncthreads();
  // phase 2: 2 passes; lane -> (n = id/8, ck = id&7); gather 8 k, store 16B
#pragma unroll
  for (int i = 0; i < 2; ++i) {
    int id = i*256 + t; int n = id >> 3, ck = id & 7;
    bf16x8 o;
#pragma unroll
    for (int j = 0; j < 8; ++j) o[j] = (bf16)tile[ck*8 + j][n];
    *(bf16x8*)&d[(long long)(n0 + n)*rows + k0 + ck*8] = o;
  }
}

// v (compact slot 2, [pair][s][(h,hd)]) -> vT ([pair][h][hd][s])
__global__ __launch_bounds__(256)
void transpose_v(const bf16* __restrict__ qkvC, bf16* __restrict__ vTb) {
  int z = blockIdx.z; int p = z >> 4, h = z & 15;
  const bf16* v = qkvC + 2*PSD + (long long)(p*CS)*CD + h*CHD;
  bf16* vt = vTb + (long long)(p*CH + h)*CHD*CS;
  __shared__ bf16 tile[32][33];
  int s0 = blockIdx.x*32, d0 = blockIdx.y*32;
  int tx = threadIdx.x % 32, ty = threadIdx.x / 32;
#pragma unroll
  for (int i = 0; i < 4; ++i)
    tile[ty + 8*i][tx] = v[(long long)(s0 + ty + 8*i)*CD + d0 + tx];
  __syncthreads();
#pragma unroll
  for (int i = 0; i < 4; ++i)
    vt[(long long)(d0 + ty + 8*i)*CS + s0 + tx] = tile[tx][ty + 8*i];
}

// ---------- async staging (global_load_lds width=16, XOR-swizzled on the global side) ----------
__device__ __forceinline__ void cp16(const bf16* g, bf16* l) {
  __builtin_amdgcn_global_load_lds((const __attribute__((address_space(1))) void*)g,
                                   (__attribute__((address_space(3))) void*)l, 16, 0, 0);
}

template<int R, int W>
__device__ __forceinline__ void stage(const bf16* __restrict__ src, int ld, bf16* dst) {
  constexpr int W8 = W/8;
  int t = threadIdx.x;
  int l = t & 63, wid = t >> 6;
#pragma unroll
  for (int i = 0; i < (R*W8)/256; ++i) {
    int idb = i*256 + wid*64;         // wave-uniform LDS base (chunk units)
    int id = idb + l;
    int row = id / W8, sl = id % W8;
    int gc = sl ^ (row & 7);          // XOR self-inverse
    cp16(src + (long long)row*ld + gc*8, dst + (long long)idb*8);
  }
}

// ---------- fused flash attention: block per (head, pair, q-tile); causal compute skipping ----------
__global__ __launch_bounds__(256)
void attn_fused(const bf16* __restrict__ qkvC, const bf16* __restrict__ vTb,
                bf16* __restrict__ aoC) {
  int h = blockIdx.x, p = blockIdx.y, qt = blockIdx.z;
  const bf16* qp = qkvC + (long long)(p*CS)*CD + h*CHD;
  const bf16* kp = qp + PSD;
  const bf16* vt = vTb + (long long)(p*CH + h)*CHD*CS;
  bf16* aop = aoC + (long long)(p*CS)*CD + h*CHD;

  __shared__ bf16 Ps[64*264];
  __shared__ float smaxL[64*4], ssumL[64*4], Lrow[64];

  int t = threadIdx.x, w = t >> 6, lane = t & 63, lr = lane & 15, quad = lane >> 4;

  floatx4 accs[4][4] = {};
  if (w <= qt) {                       // waves beyond qt have fully-masked columns
#pragma unroll
    for (int kk = 0; kk < 2; ++kk) {
      int c = kk*4 + quad;
      bf16x8 af[4], bfr[4];
#pragma unroll
      for (int i = 0; i < 4; ++i) {
        af[i]  = *(const bf16x8*)(qp + (long long)(qt*64 + i*16 + lr)*CD + c*8);
        bfr[i] = *(const bf16x8*)(kp + (long long)(w*64  + i*16 + lr)*CD + c*8);
      }
#pragma unroll
      for (int i = 0; i < 4; ++i)
#pragma unroll
        for (int j = 0; j < 4; ++j)
          accs[i][j] = __builtin_amdgcn_mfma_f32_16x16x32_bf16(af[i], bfr[j], accs[i][j], 0, 0, 0);
    }
  }
  float rmax[4][4];
#pragma unroll
  for (int i = 0; i < 4; ++i)
#pragma unroll
    for (int r = 0; r < 4; ++r) {
      int qrow = qt*64 + i*16 + quad*4 + r;
      float m = -3.0e38f;
#pragma unroll
      for (int j = 0; j < 4; ++j) {
        int kcol = w*64 + j*16 + lr;
        float s = accs[i][j][r]*0.125f;
        s = (kcol <= qrow) ? s : -3.0e38f;
        accs[i][j][r] = s;
        m = fmaxf(m, s);
      }
      rmax[i][r] = m;
    }
#pragma unroll
  for (int off = 1; off <= 8; off <<= 1)
#pragma unroll
    for (int i = 0; i < 4; ++i)
#pragma unroll
      for (int r = 0; r < 4; ++r) rmax[i][r] = fmaxf(rmax[i][r], __shfl_xor(rmax[i][r], off));
  if (lr == 0)
#pragma unroll
    for (int i = 0; i < 4; ++i)
#pragma unroll
      for (int r = 0; r < 4; ++r) smaxL[(i*16 + quad*4 + r)*4 + w] = rmax[i][r];
  __syncthreads();
  float rsum[4][4];
#pragma unroll
  for (int i = 0; i < 4; ++i)
#pragma unroll
    for (int r = 0; r < 4; ++r) {
      floatx4 mv = *(const floatx4*)&smaxL[(i*16 + quad*4 + r)*4];
      float M = fmaxf(fmaxf(mv[0], mv[1]), fmaxf(mv[2], mv[3]));
      float srow = 0.f;
#pragma unroll
      for (int j = 0; j < 4; ++j) {
        float pp = __expf(accs[i][j][r] - M);
        accs[i][j][r] = pp;
        srow += pp;
      }
      rsum[i][r] = srow;
    }
#pragma unroll
  for (int off = 1; off <= 8; off <<= 1)
#pragma unroll
    for (int i = 0; i < 4; ++i)
#pragma unroll
      for (int r = 0; r < 4; ++r) rsum[i][r] += __shfl_xor(rsum[i][r], off);
  if (lr == 0)
#pragma unroll
    for (int i = 0; i < 4; ++i)
#pragma unroll
      for (int r = 0; r < 4; ++r) ssumL[(i*16 + quad*4 + r)*4 + w] = rsum[i][r];
  __syncthreads();
  if (w == 0 && lr == 0) {
#pragma unroll
    for (int i = 0; i < 4; ++i)
#pragma unroll
      for (int r = 0; r < 4; ++r) {
        int m = i*16 + quad*4 + r;
        floatx4 sv = *(const floatx4*)&ssumL[m*4];
        Lrow[m] = sv[0] + sv[1] + sv[2] + sv[3];
      }
  }
  if (w <= qt) {                       // only valid columns are ever read back
#pragma unroll
    for (int i = 0; i < 4; ++i)
#pragma unroll
      for (int j = 0; j < 4; ++j)
#pragma unroll
        for (int r = 0; r < 4; ++r)
          Ps[(i*16 + quad*4 + r)*264 + w*64 + j*16 + lr] = (bf16)accs[i][j][r];
  }
  __syncthreads();
  floatx4 acco[4] = {};
  int ksMax = (qt + 1)*2;              // chunks c = ks*4+quad < (qt+1)*8  <=> s < (qt+1)*64
  for (int ks = 0; ks < ksMax; ++ks) {
    int c = ks*4 + quad;
    bf16x8 ap = *(const bf16x8*)(Ps + (w*16 + lr)*264 + c*8);
#pragma unroll
    for (int j = 0; j < 4; ++j) {
      bf16x8 bv = *(const bf16x8*)(vt + (long long)(j*16 + lr)*CS + c*8);
      acco[j] = __builtin_amdgcn_mfma_f32_16x16x32_bf16(ap, bv, acco[j], 0, 0, 0);
    }
  }
#pragma unroll
  for (int r = 0; r < 4; ++r) {
    int orow = w*16 + quad*4 + r;
    float inv = 1.f / Lrow[orow];
#pragma unroll
    for (int j = 0; j < 4; ++j)
      aop[(long long)(qt*64 + orow)*CD + j*16 + lr] = (bf16)(acco[j][r]*inv);
  }
}

// ---------- layernorms (vectorized) ----------
// h = LN(x + WoPartial0 + WoPartial1); writes f32 + bf16 (compact rows)
__global__ __launch_bounds__(256)
void ln1_kernel(const float* __restrict__ x, const float* __restrict__ PbF,
                const float* __restrict__ gamma, const float* __restrict__ beta,
                float* __restrict__ h, bf16* __restrict__ hbf, const int* __restrict__ pairBE) {
  int row = blockIdx.x;                     // 0..4095 compact
  int pbe = pairBE[row >> 8]; int pb = pbe & 255, pe = pbe >> 8;
  int t = threadIdx.x;
  float4 a = ((const float4*)(x + ((long long)pb*CS + (row & 255))*CD))[t];
  float4 b = ((const float4*)(PbF + (long long)row*CD))[t];
  float4 c = ((const float4*)(PbF + PSD + (long long)row*CD))[t];
  float v0 = a.x + b.x + c.x, v1 = a.y + b.y + c.y;
  float v2 = a.z + b.z + c.z, v3 = a.w + b.w + c.w;
  float s  = v0 + v1 + v2 + v3;
  float s2 = v0*v0 + v1*v1 + v2*v2 + v3*v3;
  int lane = t & 63, wave = t >> 6;
  for (int off = 32; off; off >>= 1) { s += __shfl_xor(s, off); s2 += __shfl_xor(s2, off); }
  __shared__ float red[8];
  if (lane == 0) { red[wave*2] = s; red[wave*2 + 1] = s2; }
  __syncthreads();
  s  = red[0] + red[2] + red[4] + red[6];
  s2 = red[1] + red[3] + red[5] + red[7];
  float mean = s * (1.f/CD);
  float rstd = rsqrtf(s2*(1.f/CD) - mean*mean + 1e-5f);
  float4 gm = ((const float4*)(gamma + (long long)pe*CD))[t];
  float4 bt = ((const float4*)(beta  + (long long)pe*CD))[t];
  float4 o;
  o.x = (v0 - mean)*rstd*gm.x + bt.x;
  o.y = (v1 - mean)*rstd*gm.y + bt.y;
  o.z = (v2 - mean)*rstd*gm.z + bt.z;
  o.w = (v3 - mean)*rstd*gm.w + bt.w;
  ((float4*)(h + (long long)row*CD))[t] = o;
  bf16x4 ob; ob[0] = (bf16)o.x; ob[1] = (bf16)o.y; ob[2] = (bf16)o.z; ob[3] = (bf16)o.w;
  ((bf16x4*)(hbf + (long long)row*CD))[t] = ob;
}

// y = epsfill( gate0*LN(h[p0]+f2[p0]) + gate1*LN(h[p1]+f2[p1]) )  — one block per (b,s) row
__global__ __launch_bounds__(256)
void ln2y_kernel(const float* __restrict__ h, const bf16* __restrict__ PbB,
                 const float* __restrict__ gamma, const float* __restrict__ beta,
                 float* __restrict__ y, const float* __restrict__ gates,
                 const int* __restrict__ pairBE, const int* __restrict__ batchPair) {
  int row = blockIdx.x;                     // 0..2047 = b*256 + s
  int b = row >> 8, sIdx = row & 255;
  int p0 = batchPair[2*b], p1 = batchPair[2*b + 1];
  int e0 = pairBE[p0] >> 8, e1 = pairBE[p1] >> 8;
  float gv0 = gates[b*CE + e0], gv1 = gates[b*CE + e1];
  long long r0 = (long long)p0*CS + sIdx, r1 = (long long)p1*CS + sIdx;
  int t = threadIdx.x;
  float4 a = ((const float4*)(h + r0*CD))[t];
  float4 c = ((const float4*)(h + r1*CD))[t];
#pragma unroll
  for (int k = 0; k < 4; ++k) {
    bf16x4 pa = ((const bf16x4*)(PbB + (long long)k*PSD + r0*CD))[t];
    bf16x4 pc = ((const bf16x4*)(PbB + (long long)k*PSD + r1*CD))[t];
    a.x += (float)pa[0]; a.y += (float)pa[1]; a.z += (float)pa[2]; a.w += (float)pa[3];
    c.x += (float)pc[0]; c.y += (float)pc[1]; c.z += (float)pc[2]; c.w += (float)pc[3];
  }
  float sA = a.x + a.y + a.z + a.w;
  float sA2 = a.x*a.x + a.y*a.y + a.z*a.z + a.w*a.w;
  float sB = c.x + c.y + c.z + c.w;
  float sB2 = c.x*c.x + c.y*c.y + c.z*c.z + c.w*c.w;
  int lane = t & 63, wave = t >> 6;
  for (int off = 32; off; off >>= 1) {
    sA += __shfl_xor(sA, off); sA2 += __shfl_xor(sA2, off);
    sB += __shfl_xor(sB, off); sB2 += __shfl_xor(sB2, off);
  }
  __shared__ float red[16];
  if (lane == 0) { red[wave*4] = sA; red[wave*4+1] = sA2; red[wave*4+2] = sB; red[wave*4+3] = sB2; }
  __syncthreads();
  sA  = red[0] + red[4] + red[8]  + red[12];
  sA2 = red[1] + red[5] + red[9]  + red[13];
  sB  = red[2] + red[6] + red[10] + red[14];
  sB2 = red[3] + red[7] + red[11] + red[15];
  float mA = sA*(1.f/CD), mB = sB*(1.f/CD);
  float rsA = rsqrtf(sA2*(1.f/CD) - mA*mA + 1e-5f);
  float rsB = rsqrtf(sB2*(1.f/CD) - mB*mB + 1e-5f);
  float4 gm0 = ((const float4*)(gamma + (long long)e0*CD))[t];
  float4 bt0 = ((const float4*)(beta  + (long long)e0*CD))[t];
  float4 gm1 = ((const float4*)(gamma + (long long)e1*CD))[t];
  float4 bt1 = ((const float4*)(beta  + (long long)e1*CD))[t];
  float4 o;
  o.x = gv0*((a.x - mA)*rsA*gm0.x + bt0.x) + gv1*((c.x - mB)*rsB*gm1.x + bt1.x);
  o.y = gv0*((a.y - mA)*rsA*gm0.y + bt0.y) + gv1*((c.y - mB)*rsB*gm1.y + bt1.y);
  o.z = gv0*((a.z - mA)*rsA*gm0.z + bt0.z) + gv1*((c.z - mB)*rsB*gm1.z + bt1.z);
  o.w = gv0*((a.w - mA)*rsA*gm0.w + bt0.w) + gv1*((c.w - mB)*rsB*gm1.w + bt1.w);
  constexpr float EF = 2.2204460492503131e-16f;
  o.x = (o.x == 0.f) ? EF : o.x;  o.y = (o.y == 0.f) ? EF : o.y;
  o.z = (o.z == 0.f) ? EF : o.z;  o.w = (o.w == 0.f) ? EF : o.w;
  ((float4*)(y + (long long)row*CD))[t] = o;
}

// ---------- MFMA GEMM on compact pairs:  C[M,N] = A[M,K] * Bt[N,K]^T ----------
enum { EPI_BF16 = 0, EPI_F32 = 1, EPI_BRELU = 2, EPI_BIASBF16 = 3 };

template<int EPI, int KS, bool A_BATCH>
__global__ __launch_bounds__(256)
void gemm_nt(const bf16* __restrict__ A, const bf16* __restrict__ Bt, void* __restrict__ Cv,
             int K /*per split*/, int lda, int ldb, int ldc,
             long long oBe, long long oBmat, long long oCmat, long long oCk,
             const float* __restrict__ bias, long long biasStride,
             const int* __restrict__ pairBE) {
  constexpr int BM = 128, BN = 128;
  int z = blockIdx.z;
  int zk = z % KS, mat = z / KS;
  int m0 = blockIdx.x * BM, n0 = blockIdx.y * BN;
  int pbe = pairBE[m0 >> 8]; int pb = pbe & 255, pe = pbe >> 8;
  const bf16* Ab = A + (A_BATCH ? ((long long)pb*CS + (m0 & 255))*lda : (long long)m0*lda)
                     + (long long)zk*K;
  const bf16* Bb = Bt + (long long)pe*oBe + (long long)mat*oBmat + (long long)zk*K
                      + (long long)n0*ldb;
  long long coff = (long long)mat*oCmat + (long long)zk*oCk;

  __shared__ bf16 As[BM*64];
  __shared__ bf16 Bs[BN*64];

  int wave = threadIdx.x >> 6;
  int lane = threadIdx.x & 63;
  int wm = wave >> 1, wn = wave & 1;
  int lr = lane & 15;
  int quad = lane >> 4;

  floatx4 acc[4][4] = {};

  for (int kt = 0; kt < K; kt += 64) {
    stage<BM, 64>(Ab + kt, lda, As);
    stage<BN, 64>(Bb + kt, ldb, Bs);
    __syncthreads();
#pragma unroll
    for (int kk = 0; kk < 2; ++kk) {
      bf16x8 af[4], bfr[4];
#pragma unroll
      for (int i = 0; i < 4; ++i) {
        int c = kk*4 + quad;
        int m = wm*64 + i*16 + lr;
        af[i]  = *(const bf16x8*)(As + m*64 + ((c ^ (m & 7))*8));
        int n = wn*64 + i*16 + lr;
        bfr[i] = *(const bf16x8*)(Bs + n*64 + ((c ^ (n & 7))*8));
      }
#pragma unroll
      for (int i = 0; i < 4; ++i)
#pragma unroll
        for (int j = 0; j < 4; ++j)
          acc[i][j] = __builtin_amdgcn_mfma_f32_16x16x32_bf16(af[i], bfr[j], acc[i][j], 0, 0, 0);
    }
    __syncthreads();
  }

#pragma unroll
  for (int j = 0; j < 4; ++j) {
    int col = n0 + wn*64 + j*16 + lr;
    float bv = 0.f;
    if constexpr (EPI == EPI_BRELU || EPI == EPI_BIASBF16)
      if (zk == 0) bv = bias[(long long)pe*biasStride + col];
#pragma unroll
    for (int i = 0; i < 4; ++i) {
#pragma unroll
      for (int r = 0; r < 4; ++r) {
        int row = m0 + wm*64 + i*16 + quad*4 + r;
        float v = acc[i][j][r] + bv;
        long long idx = coff + (long long)row*ldc + col;
        if constexpr (EPI == EPI_BF16)          ((bf16*)Cv)[idx] = (bf16)v;
        else if constexpr (EPI == EPI_F32)      ((float*)Cv)[idx] = v;
        else if constexpr (EPI == EPI_BRELU)    ((bf16*)Cv)[idx] = (bf16)fmaxf(v, 0.f);
        else                                    ((bf16*)Cv)[idx] = (bf16)v;
      }
    }
  }
}

// ---------- launch ----------
extern "C" void kernel_launch(void* const* d_in, const int* in_sizes, int n_in,
                              void* d_out, int out_size, void* d_ws, size_t ws_size,
                              hipStream_t stream) {
  const float* x       = (const float*)d_in[0];
  const float* noise   = (const float*)d_in[2];
  const float* w_gate  = (const float*)d_in[3];
  const float* w_noise = (const float*)d_in[4];
  const float* Wq      = (const float*)d_in[5];
  const float* Wk      = (const float*)d_in[6];
  const float* Wv      = (const float*)d_in[7];
  const float* Wo      = (const float*)d_in[8];
  const float* W1      = (const float*)d_in[9];
  const float* b1      = (const float*)d_in[10];
  const float* W2      = (const float*)d_in[11];
  const float* b2      = (const float*)d_in[12];
  const float* g1      = (const float*)d_in[13];
  const float* be1     = (const float*)d_in[14];
  const float* g2      = (const float*)d_in[15];
  const float* be2     = (const float*)d_in[16];

  char* ws = (char*)d_ws;
  float* y    = (float*)d_out;
  float* loss = y + (size_t)BSD;

  float* part  = (float*)(ws + OFF_PART);
  float* clean = (float*)(ws + OFF_CLEAN);
  float* raw   = (float*)(ws + OFF_RAW);
  float* gates = (float*)(ws + OFF_GATES);
  int*   eact  = (int*)  (ws + OFF_EACT);
  int*   pairBE= (int*)  (ws + OFF_PBE);
  int*   batchPair = (int*)(ws + OFF_BP);
  bf16*  xbf   = (bf16*) (ws + OFF_XBF);
  bf16*  wT    = (bf16*) (ws + OFF_WT);
  bf16*  w1T   = (bf16*) (ws + OFF_W1T);
  bf16*  w2T   = (bf16*) (ws + OFF_W2T);
  bf16*  qkvC  = (bf16*) (ws + OFF_QKV);
  bf16*  aoC   = (bf16*) (ws + OFF_AO);
  bf16*  f1    = (bf16*) (ws + OFF_F1);
  bf16*  vTb   = (bf16*) (ws + OFF_VT);
  float* PbF   = (float*)(ws + OFF_PB);
  bf16*  PbB   = (bf16*) (ws + OFF_PB);
  float* h     = (float*)(ws + OFF_H);
  bf16*  hbf   = (bf16*) (ws + OFF_HBF);

  cvt_xsum<<<64, 256, 0, stream>>>(x, xbf, part);
  gate_dots<<<32, 256, 0, stream>>>(part, w_gate, w_noise, clean, raw);
  gating_kernel<<<1, 64, 0, stream>>>(clean, raw, noise, gates, eact, pairBE, batchPair, loss);
  transcvt_all<<<12288, 256, 0, stream>>>(Wq, Wk, Wv, Wo, W1, W2, wT, w1T, w2T, eact);

  // q,k,v = x @ {Wq,Wk,Wv}  (compact M = 16 pairs x 256)
  gemm_nt<EPI_BF16, 1, true><<<dim3(32, 8, 3), 256, 0, stream>>>(
      xbf, wT, qkvC, 1024, 1024, 1024, 1024,
      4*DD, DD, PSD, 0, nullptr, 0, pairBE);

  transpose_v<<<dim3(8, 2, 256), 256, 0, stream>>>(qkvC, vTb);

  // fused attention: (head, pair, q-tile), causal skipping
  attn_fused<<<dim3(CH, 16, 4), 256, 0, stream>>>(qkvC, vTb, aoC);

  // o = ao @ Wo, split-K=2 -> f32 partials
  gemm_nt<EPI_F32, 2, false><<<dim3(32, 8, 2), 256, 0, stream>>>(
      aoC, wT + 3*DD, PbF, 512, 1024, 1024, 1024,
      4*DD, 0, 0, PSD, nullptr, 0, pairBE);

  // h = LN(x + o)
  ln1_kernel<<<4096, 256, 0, stream>>>(x, PbF, g1, be1, h, hbf, pairBE);

  // f1 = relu(h @ W1 + b1)   (f1 overlays qkv+ao)
  gemm_nt<EPI_BRELU, 1, false><<<dim3(32, 32, 1), 256, 0, stream>>>(
      hbf, w1T, f1, 1024, 1024, 1024, 4096,
      DFF, 0, 0, 0, b1, CFF, pairBE);

  // f2 = f1 @ W2 + b2, split-K=4 -> bf16 partials
  gemm_nt<EPI_BIASBF16, 4, false><<<dim3(32, 8, 4), 256, 0, stream>>>(
      f1, w2T, PbB, 1024, 4096, 4096, 1024,
      DFF, 0, 0, PSD, b2, CD, pairBE);

  // y = epsfill( sum of gate * LN(h + f2) over the batch's 2 active pairs )
  ln2y_kernel<<<2048, 256, 0, stream>>>(h, PbB, g2, be2, y, gates, pairBE, batchPair);
}